// Round 4
// baseline (350.327 us; speedup 1.0000x reference)
//
#include <hip/hip_runtime.h>
#include <hip/hip_fp16.h>
#include <math.h>

#define N_NODES 10000
#define N_EDGES 160000
#define N_GRAPHS 64

using half8 = __attribute__((ext_vector_type(8))) _Float16;
using floatx4 = __attribute__((ext_vector_type(4))) float;
using h2v = __attribute__((ext_vector_type(2))) _Float16;

// raw f16 fragment word: 4 halfs (NV=1) or 8 halfs (NV=2)
template <int NV> struct KW;
template <> struct KW<1> { using T = uint2; };
template <> struct KW<2> { using T = uint4; };

__device__ inline void cvt_kv(const uint2& w, float4* dst) {
  float2 a = __half22float2(*reinterpret_cast<const __half2*>(&w.x));
  float2 b = __half22float2(*reinterpret_cast<const __half2*>(&w.y));
  dst[0] = make_float4(a.x, a.y, b.x, b.y);
}
__device__ inline void cvt_kv(const uint4& w, float4* dst) {
  float2 a = __half22float2(*reinterpret_cast<const __half2*>(&w.x));
  float2 b = __half22float2(*reinterpret_cast<const __half2*>(&w.y));
  float2 c = __half22float2(*reinterpret_cast<const __half2*>(&w.z));
  float2 d = __half22float2(*reinterpret_cast<const __half2*>(&w.w));
  dst[0] = make_float4(a.x, a.y, b.x, b.y);
  dst[1] = make_float4(c.x, c.y, d.x, d.y);
}

// Q.K dot in f16 via v_dot2_f32_f16 (f32 accumulate) — kills the K-side cvt.
#if __has_builtin(__builtin_amdgcn_fdot2)
__device__ inline float dot_qk(const uint2& k, const uint2& q, float c) {
  c = __builtin_amdgcn_fdot2(__builtin_bit_cast(h2v, k.x), __builtin_bit_cast(h2v, q.x), c, false);
  c = __builtin_amdgcn_fdot2(__builtin_bit_cast(h2v, k.y), __builtin_bit_cast(h2v, q.y), c, false);
  return c;
}
__device__ inline float dot_qk(const uint4& k, const uint4& q, float c) {
  c = __builtin_amdgcn_fdot2(__builtin_bit_cast(h2v, k.x), __builtin_bit_cast(h2v, q.x), c, false);
  c = __builtin_amdgcn_fdot2(__builtin_bit_cast(h2v, k.y), __builtin_bit_cast(h2v, q.y), c, false);
  c = __builtin_amdgcn_fdot2(__builtin_bit_cast(h2v, k.z), __builtin_bit_cast(h2v, q.z), c, false);
  c = __builtin_amdgcn_fdot2(__builtin_bit_cast(h2v, k.w), __builtin_bit_cast(h2v, q.w), c, false);
  return c;
}
#else
__device__ inline float dot_qk(const uint2& k, const uint2& q, float c) {
  float4 kk[1], qq[1];
  cvt_kv(k, kk); cvt_kv(q, qq);
  return c + qq[0].x * kk[0].x + qq[0].y * kk[0].y + qq[0].z * kk[0].z + qq[0].w * kk[0].w;
}
__device__ inline float dot_qk(const uint4& k, const uint4& q, float c) {
  float4 kk[2], qq[2];
  cvt_kv(k, kk); cvt_kv(q, qq);
  c += qq[0].x * kk[0].x + qq[0].y * kk[0].y + qq[0].z * kk[0].z + qq[0].w * kk[0].w;
  c += qq[1].x * kk[1].x + qq[1].y * kk[1].y + qq[1].z * kk[1].z + qq[1].w * kk[1].w;
  return c;
}
#endif

// ---------------------------------------------------------------------------
// MFMA GEMM: [Q|G|K|V|S] = A[M,K]_f16 @ Wp_f16 + bias_f32.
// ---------------------------------------------------------------------------
template <int K, int HD, int DOUT>
__global__ __launch_bounds__(256) void gemm_mfma(
    const __half* __restrict__ A, const __half* __restrict__ Wp,
    const float* __restrict__ bias, __half* __restrict__ QS,
    __half* __restrict__ KV, int M) {
  constexpr int QSS = HD + 64 + DOUT;
  constexpr int KVS = 2 * HD;
  constexpr int KS = K / 32;
  __shared__ __half st[64][72];
  const int tid = threadIdx.x;
  const int wave = tid >> 6, lane = tid & 63;
  const int quad = lane >> 4, n16 = lane & 15;
  const int row0 = blockIdx.y * 64;
  const int col0 = blockIdx.x * 64;
  const int nblk0 = blockIdx.x * 4;

  const int arow = min(row0 + wave * 16 + n16, M - 1);
  half8 afrag[KS];
#pragma unroll
  for (int s = 0; s < KS; ++s)
    afrag[s] = *reinterpret_cast<const half8*>(A + (size_t)arow * K + s * 32 + quad * 8);

  floatx4 acc[4];
#pragma unroll
  for (int t = 0; t < 4; ++t) {
    acc[t] = (floatx4){0.f, 0.f, 0.f, 0.f};
#pragma unroll
    for (int s = 0; s < KS; ++s) {
      half8 bf = *reinterpret_cast<const half8*>(
          Wp + (((size_t)(nblk0 + t) * KS + s) * 64 + lane) * 8);
      acc[t] = __builtin_amdgcn_mfma_f32_16x16x32_f16(afrag[s], bf, acc[t], 0, 0, 0);
    }
  }

#pragma unroll
  for (int t = 0; t < 4; ++t) {
    float bv = bias[col0 + t * 16 + n16];
#pragma unroll
    for (int r = 0; r < 4; ++r)
      st[wave * 16 + quad * 4 + r][t * 16 + n16] = __float2half(acc[t][r] + bv);
  }
  __syncthreads();

  __half* dp;
  int colb, stride;
  if (col0 < HD + 64) {
    dp = QS; colb = col0; stride = QSS;
  } else if (col0 < 3 * HD + 64) {
    dp = KV; colb = col0 - HD - 64; stride = KVS;
  } else {
    dp = QS; colb = HD + 64 + (col0 - 3 * HD - 64); stride = QSS;
  }
  for (int c = tid; c < 512; c += 256) {
    int r = c >> 3, seg = c & 7;
    int row = row0 + r;
    if (row < M)
      *reinterpret_cast<uint4*>(dp + (size_t)row * stride + colb + seg * 8) =
          *reinterpret_cast<const uint4*>(&st[r][seg * 8]);
  }
}

// ---------------------------------------------------------------------------
// Pack weights into B-fragment order (f16), with fused G columns.
// ---------------------------------------------------------------------------
__device__ inline void pack_layer(int i, int K, int HD, int DOUT, float scale,
                                  const float* wq, const float* wk,
                                  const float* wv, const float* wsk,
                                  const float* we, const float* bq,
                                  const float* bk, const float* bv,
                                  const float* bs, __half* Wp, float* bcat) {
  const int W = 3 * HD + DOUT + 64;
  const int KS = K / 32;
  if (i < K * W) {
    int j = i & 7, lane = (i >> 3) & 63, fs = i >> 9;
    int nblk = fs / KS, s = fs - nblk * KS;
    int quad = lane >> 4, n = lane & 15;
    int k = s * 32 + quad * 8 + j, c = nblk * 16 + n;
    float v;
    if (c < HD) {
      v = wq[k * HD + c] * scale;
    } else if (c < HD + 64) {
      int gi = c - HD, hh = gi >> 4, d = gi & 15;
      float a = 0.f;
      for (int cc = 0; cc < DOUT; ++cc)
        a += wq[k * HD + hh * DOUT + cc] * we[d * HD + hh * DOUT + cc];
      v = a * scale;
    } else if (c < 2 * HD + 64) {
      v = wk[k * HD + (c - HD - 64)];
    } else if (c < 3 * HD + 64) {
      v = wv[k * HD + (c - 2 * HD - 64)];
    } else {
      v = wsk[k * DOUT + (c - 3 * HD - 64)];
    }
    Wp[i] = __float2half(v);
  } else {
    int c = i - K * W;
    float v;
    if (c < HD) {
      v = bq[c] * scale;
    } else if (c < HD + 64) {
      int gi = c - HD, hh = gi >> 4, d = gi & 15;
      float a = 0.f;
      for (int cc = 0; cc < DOUT; ++cc)
        a += bq[hh * DOUT + cc] * we[d * HD + hh * DOUT + cc];
      v = a * scale;
    } else if (c < 2 * HD + 64) {
      v = bk[c - HD - 64];
    } else if (c < 3 * HD + 64) {
      v = bv[c - 2 * HD - 64];
    } else {
      v = bs[c - 3 * HD - 64];
    }
    bcat[c] = v;
  }
}

#define T1 115584            // 128*896 + 896
#define T2 227904            // T1 + 64*1728 + 1728
#define T3 343488            // T2 + 128*896 + 896
#define TCONV (N_NODES * 32) // x float4 count
#define TTOT (T3 + TCONV)

__global__ void pack_all(
    const float* wq1, const float* wk1, const float* wv1, const float* ws1,
    const float* we1, const float* bq1, const float* bk1, const float* bv1,
    const float* bs1,
    const float* wq2, const float* wk2, const float* wv2, const float* ws2,
    const float* we2, const float* bq2, const float* bk2, const float* bv2,
    const float* bs2,
    const float* wq3, const float* wk3, const float* wv3, const float* ws3,
    const float* we3, const float* bq3, const float* bk3, const float* bv3,
    const float* bs3,
    __half* W1, float* b1, __half* W2, float* b2, __half* W3, float* b3,
    const float* x, __half* x16) {
  const float SC1 = 0.125f, SC2 = 0.08838834764831845f;
  for (int i = blockIdx.x * blockDim.x + threadIdx.x; i < TTOT;
       i += gridDim.x * blockDim.x) {
    if (i < T1)
      pack_layer(i, 128, 256, 64, SC1, wq1, wk1, wv1, ws1, we1, bq1, bk1, bv1, bs1, W1, b1);
    else if (i < T2)
      pack_layer(i - T1, 64, 512, 128, SC2, wq2, wk2, wv2, ws2, we2, bq2, bk2, bv2, bs2, W2, b2);
    else if (i < T3)
      pack_layer(i - T2, 128, 256, 64, SC1, wq3, wk3, wv3, ws3, we3, bq3, bk3, bv3, bs3, W3, b3);
    else {
      int k = i - T3;
      float4 v = reinterpret_cast<const float4*>(x)[k];
      __half2* o = reinterpret_cast<__half2*>(x16) + 2 * k;
      o[0] = __floats2half2_rn(v.x, v.y);
      o[1] = __floats2half2_rn(v.z, v.w);
    }
  }
}

// ---------------------------------------------------------------------------
// CSR build over dst
// ---------------------------------------------------------------------------
__global__ void count_dst(const int* __restrict__ dst, int* __restrict__ cnt) {
  int e = blockIdx.x * blockDim.x + threadIdx.x;
  if (e < N_EDGES) atomicAdd(&cnt[dst[e]], 1);
}

// Fused: exclusive scan of degrees -> offs, AND degree-descending counting
// sort of nodes -> perm (schedules heavy nodes first in edge_attn).
__global__ __launch_bounds__(1024) void scan_offs(const int* __restrict__ cnt,
                                                  int* __restrict__ offs,
                                                  int* __restrict__ perm) {
  __shared__ int part[1024];
  __shared__ int hist[256], hstart[256], hcur[256];
  const int t = threadIdx.x;
  const int chunk = (N_NODES + 1023) / 1024;
  const int b = t * chunk;
  const int e = min(N_NODES, b + chunk);
  if (t < 256) { hist[t] = 0; hcur[t] = 0; }
  __syncthreads();
  int s = 0;
  for (int i = b; i < e; ++i) {
    int d = cnt[i];
    s += d;
    atomicAdd(&hist[min(d, 255)], 1);
  }
  part[t] = s;
  __syncthreads();
  for (int off = 1; off < 1024; off <<= 1) {
    int v = (t >= off) ? part[t - off] : 0;
    __syncthreads();
    part[t] += v;
    __syncthreads();
  }
  if (t == 0) {
    int acc = 0;
    for (int bk = 255; bk >= 0; --bk) { hstart[bk] = acc; acc += hist[bk]; }
    offs[N_NODES] = part[1023];
  }
  __syncthreads();
  int pre = (t == 0) ? 0 : part[t - 1];
  for (int i = b; i < e; ++i) {
    offs[i] = pre;
    int d = cnt[i];
    pre += d;
    int bkt = min(d, 255);
    int pos = hstart[bkt] + atomicAdd(&hcur[bkt], 1);
    perm[pos] = i;
  }
}

__global__ void scatter_csr(const int* __restrict__ src, const int* __restrict__ dst,
                            const float* __restrict__ edge_attr,
                            const int* __restrict__ offs, int* __restrict__ cursor,
                            int* __restrict__ csr_src, float* __restrict__ csr_ea) {
  int e = blockIdx.x * blockDim.x + threadIdx.x;
  if (e < N_EDGES) {
    int d = dst[e];
    int pos = offs[d] + atomicAdd(&cursor[d], 1);
    csr_src[pos] = src[e];
    float4* o4 = reinterpret_cast<float4*>(csr_ea + (size_t)pos * 16);
    const float4* s4 = reinterpret_cast<const float4*>(edge_attr + (size_t)e * 16);
    o4[0] = s4[0]; o4[1] = s4[1]; o4[2] = s4[2]; o4[3] = s4[3];
  }
}

// ---------------------------------------------------------------------------
// Fused edge kernel. CHANGES vs prior round:
//  (1) TWO nodes per wave with cross-node overlap: merged prologue issues
//      both nodes' perm/offs/Q/G/csr_src loads in one batch (one exposed
//      latency, not two serial chains); after node A's edge loop, node B's
//      first KV group is STAGED, then A's ~500-VALU epilogue runs while B's
//      loads are in flight (T14 async-stage pattern). Rationale: avg degree
//      16 -> per-node fixed chains dominate wave lifetime (measured VALU
//      floor 18us vs 51us dur at 36% VALUBusy).
//  (2) Q.K via v_dot2_f32_f16 (f16 dot, f32 accum) - removes K-side cvt.
//  Depth-3 intra-node pipeline retained.
// ---------------------------------------------------------------------------
template <int DOUT, bool W32>
__global__ __launch_bounds__(128) void edge_attn(
    const __half* __restrict__ QS, const __half* __restrict__ KV,
    const float* __restrict__ we, const int* __restrict__ csr_src,
    const float* __restrict__ csr_ea, const int* __restrict__ offs,
    const int* __restrict__ perm, float* __restrict__ out,
    __half* __restrict__ out16) {
  constexpr int HD = 4 * DOUT;
  constexpr int QSS = HD + 64 + DOUT;
  constexpr int KVS = 2 * HD;
  constexpr int NV = DOUT / 64;
  using KWT = typename KW<NV>::T;

  const int lane = threadIdx.x & 63;
  const int h = lane >> 4, t16 = lane & 15;
  const int c0 = t16 * 4 * NV;
  // 2 nodes per wave, adjacent perm entries (similar degree -> balanced)
  const int pbase = (blockIdx.x * 2 + (threadIdx.x >> 6)) * 2;
  const int nA = perm[pbase], nB = perm[pbase + 1];
  const __half* baseA = QS + (size_t)nA * QSS;
  const __half* baseB = QS + (size_t)nB * QSS;

  // ---- merged prologue: all independent loads for BOTH nodes ----
  const int s0A = offs[nA], s1A = offs[nA + 1];
  const int s0B = offs[nB], s1B = offs[nB + 1];
  KWT qwA = *reinterpret_cast<const KWT*>(baseA + h * DOUT + c0);
  KWT qwB = *reinterpret_cast<const KWT*>(baseB + h * DOUT + c0);
  const float gA = __half2float(baseA[HD + h * 16 + t16]);
  const float gB = __half2float(baseB[HD + h * 16 + t16]);
  int idxA = (s1A > s0A) ? csr_src[s0A + min(lane, s1A - s0A - 1)] : 0;
  int idxB = (s1B > s0B) ? csr_src[s0B + min(lane, s1B - s0B - 1)] : 0;

  // shared pipeline state (sequential node processing -> one set)
  float ea0[4], ea1[4], ea2[4];
  KWT kr0[4], vr0[4], kr1[4], vr1[4], kr2[4], vr2[4];
  float4 acc[NV];
  float lsum, tacc;

  auto run_node = [&](int s0, int s1, int idx0, float g, KWT qw, bool pre0) {
    lsum = 0.f; tacc = 0.f;
#pragma unroll
    for (int v = 0; v < NV; ++v) acc[v] = make_float4(0.f, 0.f, 0.f, 0.f);
    int idx = idx0;
    for (int cb = s0; cb < s1; cb += 64) {
      const int m = min(64, s1 - cb);
      if (cb != s0) idx = csr_src[cb + min(lane, m - 1)];
      const int ng = m >> 2;

      auto load_grp = [&](int gb, float (&ea)[4], KWT (&kr)[4], KWT (&vr)[4]) {
        const int bi = cb + gb;
#pragma unroll
        for (int j = 0; j < 4; ++j) ea[j] = csr_ea[(size_t)(bi + j) * 16 + t16];
#pragma unroll
        for (int j = 0; j < 4; ++j) {
          int sj = __shfl(idx, gb + j);
          const __half* rb = KV + (size_t)sj * KVS + h * DOUT + c0;
          kr[j] = *reinterpret_cast<const KWT*>(rb);
          vr[j] = *reinterpret_cast<const KWT*>(rb + HD);
        }
      };

      auto compute_grp = [&](float (&ea)[4], KWT (&kr)[4], KWT (&vr)[4]) {
        float a[4];
#pragma unroll
        for (int j = 0; j < 4; ++j) a[j] = dot_qk(kr[j], qw, ea[j] * g);
#pragma unroll
        for (int j = 0; j < 4; ++j) {
          a[j] += __shfl_xor(a[j], 1);
          a[j] += __shfl_xor(a[j], 2);
          a[j] += __shfl_xor(a[j], 4);
          a[j] += __shfl_xor(a[j], 8);
        }
        float p0 = __expf(a[0]), p1 = __expf(a[1]);
        float p2 = __expf(a[2]), p3 = __expf(a[3]);
        lsum += p0 + p1 + p2 + p3;
        tacc += p0 * ea[0] + p1 * ea[1] + p2 * ea[2] + p3 * ea[3];
        float pj[4] = {p0, p1, p2, p3};
#pragma unroll
        for (int j = 0; j < 4; ++j) {
          float4 vv[NV];
          cvt_kv(vr[j], vv);
#pragma unroll
          for (int v = 0; v < NV; ++v) {
            acc[v].x += pj[j] * vv[v].x;
            acc[v].y += pj[j] * vv[v].y;
            acc[v].z += pj[j] * vv[v].z;
            acc[v].w += pj[j] * vv[v].w;
          }
        }
      };

      if (ng) {
        if (!(cb == s0 && pre0)) load_grp(0, ea0, kr0, vr0);
        if (ng > 1) load_grp(4, ea1, kr1, vr1);
        int gi = 0;
        for (;;) {
          if (gi + 2 < ng) load_grp((gi + 2) * 4, ea2, kr2, vr2);
          compute_grp(ea0, kr0, vr0);
          if (++gi >= ng) break;
          if (gi + 2 < ng) load_grp((gi + 2) * 4, ea0, kr0, vr0);
          compute_grp(ea1, kr1, vr1);
          if (++gi >= ng) break;
          if (gi + 2 < ng) load_grp((gi + 2) * 4, ea1, kr1, vr1);
          compute_grp(ea2, kr2, vr2);
          if (++gi >= ng) break;
        }
      }

      for (int e = ng * 4; e < m; ++e) {
        int sj = __shfl(idx, e);
        float ea0s = csr_ea[(size_t)(cb + e) * 16 + t16];
        const __half* rb = KV + (size_t)sj * KVS + h * DOUT + c0;
        KWT kw = *reinterpret_cast<const KWT*>(rb);
        KWT vw = *reinterpret_cast<const KWT*>(rb + HD);
        float a = dot_qk(kw, qw, ea0s * g);
        a += __shfl_xor(a, 1);
        a += __shfl_xor(a, 2);
        a += __shfl_xor(a, 4);
        a += __shfl_xor(a, 8);
        float p = __expf(a);
        lsum += p;
        tacc += p * ea0s;
        float4 vv[NV];
        cvt_kv(vw, vv);
#pragma unroll
        for (int v = 0; v < NV; ++v) {
          acc[v].x += p * vv[v].x;
          acc[v].y += p * vv[v].y;
          acc[v].z += p * vv[v].z;
          acc[v].w += p * vv[v].w;
        }
      }
    }
  };

  auto epi = [&](int n, const __half* base) {
    float invl = (lsum > 0.f) ? 1.f / lsum : 0.f;
    float tn = tacc * invl;
    float4 val[NV];
#pragma unroll
    for (int v = 0; v < NV; ++v) {
      val[v].x = acc[v].x * invl; val[v].y = acc[v].y * invl;
      val[v].z = acc[v].z * invl; val[v].w = acc[v].w * invl;
    }
#pragma unroll
    for (int d = 0; d < 16; ++d) {
      float td = __shfl(tn, (lane & 48) | d);
      const float* wb = we + d * HD + h * DOUT + c0;
#pragma unroll
      for (int v = 0; v < NV; ++v) {
        float4 w4 = *reinterpret_cast<const float4*>(wb + 4 * v);
        val[v].x += td * w4.x; val[v].y += td * w4.y;
        val[v].z += td * w4.z; val[v].w += td * w4.w;
      }
    }
#pragma unroll
    for (int v = 0; v < NV; ++v) {
      val[v].x += __shfl_xor(val[v].x, 16); val[v].x += __shfl_xor(val[v].x, 32);
      val[v].y += __shfl_xor(val[v].y, 16); val[v].y += __shfl_xor(val[v].y, 32);
      val[v].z += __shfl_xor(val[v].z, 16); val[v].z += __shfl_xor(val[v].z, 32);
      val[v].w += __shfl_xor(val[v].w, 16); val[v].w += __shfl_xor(val[v].w, 32);
    }
    if (h == 0) {
      KWT sw = *reinterpret_cast<const KWT*>(base + HD + 64 + c0);
      float4 sk[NV];
      cvt_kv(sw, sk);
#pragma unroll
      for (int v = 0; v < NV; ++v) {
        float4 o;
        o.x = 0.25f * val[v].x + sk[v].x;
        o.y = 0.25f * val[v].y + sk[v].y;
        o.z = 0.25f * val[v].z + sk[v].z;
        o.w = 0.25f * val[v].w + sk[v].w;
        o.x = (o.x > 0.f) ? o.x : expm1f(o.x);
        o.y = (o.y > 0.f) ? o.y : expm1f(o.y);
        o.z = (o.z > 0.f) ? o.z : expm1f(o.z);
        o.w = (o.w > 0.f) ? o.w : expm1f(o.w);
        if (W32)
          *reinterpret_cast<float4*>(out + (size_t)n * DOUT + c0 + 4 * v) = o;
        __half2* o16 = reinterpret_cast<__half2*>(out16 + (size_t)n * DOUT + c0 + 4 * v);
        o16[0] = __floats2half2_rn(o.x, o.y);
        o16[1] = __floats2half2_rn(o.z, o.w);
      }
    }
  };

  // ---- node A ----
  run_node(s0A, s1A, idxA, gA, qwA, false);

  // ---- stage node B's first KV group, then run A's epilogue over it ----
  bool preB = false;
  {
    const int mB = min(64, s1B - s0B);
    if (mB >= 4) {
#pragma unroll
      for (int j = 0; j < 4; ++j) ea0[j] = csr_ea[(size_t)(s0B + j) * 16 + t16];
#pragma unroll
      for (int j = 0; j < 4; ++j) {
        int sj = __shfl(idxB, j);
        const __half* rb = KV + (size_t)sj * KVS + h * DOUT + c0;
        kr0[j] = *reinterpret_cast<const KWT*>(rb);
        vr0[j] = *reinterpret_cast<const KWT*>(rb + HD);
      }
      preB = true;
    }
  }
  epi(nA, baseA);

  // ---- node B ----
  run_node(s0B, s1B, idxB, gB, qwB, preB);
  epi(nB, baseB);
}

// ---------------------------------------------------------------------------
// Global mean pool (batch sorted -> contiguous per-graph ranges)
// ---------------------------------------------------------------------------
__device__ inline int lower_bound(const int* b, int n, int v) {
  int lo = 0, hi = n;
  while (lo < hi) {
    int mid = (lo + hi) >> 1;
    if (b[mid] < v) lo = mid + 1; else hi = mid;
  }
  return lo;
}

__global__ __launch_bounds__(256) void pool_all(const float* __restrict__ h,
                                                const int* __restrict__ batch,
                                                float* __restrict__ out) {
  const int g = blockIdx.x;
  const int start = lower_bound(batch, N_NODES, g);
  const int end = lower_bound(batch, N_NODES, g + 1);
  const int c = threadIdx.x & 63, j = threadIdx.x >> 6;
  float s = 0.f;
  for (int n = start + j; n < end; n += 4) s += h[(size_t)n * 64 + c];
  __shared__ float red[4][64];
  red[j][c] = s;
  __syncthreads();
  if (j == 0) {
    float tot = red[0][c] + red[1][c] + red[2][c] + red[3][c];
    out[g * 64 + c] = tot / (float)max(end - start, 1);
  }
}

// ---------------------------------------------------------------------------
extern "C" void kernel_launch(void* const* d_in, const int* in_sizes, int n_in,
                              void* d_out, int out_size, void* d_ws, size_t ws_size,
                              hipStream_t stream) {
  const float* x = (const float*)d_in[0];
  const int* edge_index = (const int*)d_in[1];
  const float* edge_attr = (const float*)d_in[2];
  const int* batch = (const int*)d_in[3];
  const int* srcp = edge_index;
  const int* dstp = edge_index + N_EDGES;

  const bool dict_order = in_sizes[5] > 1024;
  const float *wq[3], *wk[3], *wv[3], *wep[3], *wsk[3], *bq[3], *bk[3], *bv[3], *bs[3];
  for (int L = 0; L < 3; ++L) {
    int b = 4 + L * 9;
    if (dict_order) {
      wq[L] = (const float*)d_in[b + 0];
      wk[L] = (const float*)d_in[b + 1];
      wv[L] = (const float*)d_in[b + 2];
      wep[L] = (const float*)d_in[b + 3];
      wsk[L] = (const float*)d_in[b + 4];
      bq[L] = (const float*)d_in[b + 5];
      bk[L] = (const float*)d_in[b + 6];
      bv[L] = (const float*)d_in[b + 7];
      bs[L] = (const float*)d_in[b + 8];
    } else {
      wq[L] = (const float*)d_in[b + 0];
      bq[L] = (const float*)d_in[b + 1];
      wk[L] = (const float*)d_in[b + 2];
      bk[L] = (const float*)d_in[b + 3];
      wv[L] = (const float*)d_in[b + 4];
      bv[L] = (const float*)d_in[b + 5];
      wep[L] = (const float*)d_in[b + 6];
      wsk[L] = (const float*)d_in[b + 7];
      bs[L] = (const float*)d_in[b + 8];
    }
  }

  // Workspace carve (bytes).
  char* p = (char*)d_ws;
  __half* qs = (__half*)p;    p += (size_t)N_NODES * 704 * 2;   // Q|G|S f16 (max L2)
  __half* kv = (__half*)p;    p += (size_t)N_NODES * 1024 * 2;  // K|V f16 (max L2)
  float* h1 = (float*)p;      p += (size_t)N_NODES * 64 * 4;
  __half* x16 = (__half*)p;   p += (size_t)N_NODES * 128 * 2;
  __half* h16 = (__half*)p;   p += (size_t)N_NODES * 128 * 2;
  __half* W1 = (__half*)p;    p += 128 * 896 * 2;
  __half* W2 = (__half*)p;    p += 64 * 1728 * 2;
  __half* W3 = (__half*)p;    p += 128 * 896 * 2;
  float* b1 = (float*)p;      p += 896 * 4;
  float* b2 = (float*)p;      p += 1728 * 4;
  float* b3 = (float*)p;      p += 896 * 4;
  float* csr_ea = (float*)p;  p += (size_t)N_EDGES * 16 * 4;
  int* cnt = (int*)p;         p += N_NODES * 4;
  int* cursor = (int*)p;      p += N_NODES * 4;
  int* offs = (int*)p;        p += (N_NODES + 1) * 4;
  int* perm = (int*)p;        p += N_NODES * 4;
  int* csr_src = (int*)p;     p += N_EDGES * 4;

  // ---- pack weights (f16 frag order, fused G cols) + x->f16 (1 launch) ----
  pack_all<<<1024, 256, 0, stream>>>(
      wq[0], wk[0], wv[0], wsk[0], wep[0], bq[0], bk[0], bv[0], bs[0],
      wq[1], wk[1], wv[1], wsk[1], wep[1], bq[1], bk[1], bv[1], bs[1],
      wq[2], wk[2], wv[2], wsk[2], wep[2], bq[2], bk[2], bv[2], bs[2],
      W1, b1, W2, b2, W3, b3, x, x16);

  // ---- CSR build over dst + degree-sorted scheduling permutation ----
  hipMemsetAsync(cnt, 0, 2 * N_NODES * sizeof(int), stream);  // cnt + cursor
  count_dst<<<(N_EDGES + 255) / 256, 256, 0, stream>>>(dstp, cnt);
  scan_offs<<<1, 1024, 0, stream>>>(cnt, offs, perm);
  scatter_csr<<<(N_EDGES + 255) / 256, 256, 0, stream>>>(srcp, dstp, edge_attr,
                                                         offs, cursor, csr_src, csr_ea);

  const int MT = (N_NODES + 63) / 64;
  // ---- layer 1: K=128, HD=256, DOUT=64 ----
  gemm_mfma<128, 256, 64><<<dim3(896 / 64, MT), 256, 0, stream>>>(x16, W1, b1, qs,
                                                                  kv, N_NODES);
  edge_attn<64, false><<<N_NODES / 4, 128, 0, stream>>>(qs, kv, wep[0], csr_src,
                                                        csr_ea, offs, perm, h1, h16);
  // ---- layer 2: K=64, HD=512, DOUT=128 ----
  gemm_mfma<64, 512, 128><<<dim3(1728 / 64, MT), 256, 0, stream>>>(h16, W2, b2, qs,
                                                                   kv, N_NODES);
  edge_attn<128, false><<<N_NODES / 4, 128, 0, stream>>>(qs, kv, wep[1], csr_src,
                                                         csr_ea, offs, perm, h1, h16);
  // ---- layer 3: K=128, HD=256, DOUT=64 ----
  gemm_mfma<128, 256, 64><<<dim3(896 / 64, MT), 256, 0, stream>>>(h16, W3, b3, qs,
                                                                  kv, N_NODES);
  edge_attn<64, true><<<N_NODES / 4, 128, 0, stream>>>(qs, kv, wep[2], csr_src,
                                                       csr_ea, offs, perm, h1, x16);

  // ---- global mean pool ----
  pool_all<<<N_GRAPHS, 256, 0, stream>>>(h1, batch, (float*)d_out);
}

// Round 5
// 329.019 us; speedup vs baseline: 1.0648x; 1.0648x over previous
//
#include <hip/hip_runtime.h>
#include <hip/hip_fp16.h>
#include <math.h>

#define N_NODES 10000
#define N_EDGES 160000
#define N_GRAPHS 64

using half8 = __attribute__((ext_vector_type(8))) _Float16;
using floatx4 = __attribute__((ext_vector_type(4))) float;
using h2v = __attribute__((ext_vector_type(2))) _Float16;

// raw f16 fragment word: 4 halfs (NV=1) or 8 halfs (NV=2)
template <int NV> struct KW;
template <> struct KW<1> { using T = uint2; };
template <> struct KW<2> { using T = uint4; };

__device__ inline void cvt_kv(const uint2& w, float4* dst) {
  float2 a = __half22float2(*reinterpret_cast<const __half2*>(&w.x));
  float2 b = __half22float2(*reinterpret_cast<const __half2*>(&w.y));
  dst[0] = make_float4(a.x, a.y, b.x, b.y);
}
__device__ inline void cvt_kv(const uint4& w, float4* dst) {
  float2 a = __half22float2(*reinterpret_cast<const __half2*>(&w.x));
  float2 b = __half22float2(*reinterpret_cast<const __half2*>(&w.y));
  float2 c = __half22float2(*reinterpret_cast<const __half2*>(&w.z));
  float2 d = __half22float2(*reinterpret_cast<const __half2*>(&w.w));
  dst[0] = make_float4(a.x, a.y, b.x, b.y);
  dst[1] = make_float4(c.x, c.y, d.x, d.y);
}

// Q.K dot in f16 via v_dot2_f32_f16 (f32 accumulate) — kills the K-side cvt.
#if __has_builtin(__builtin_amdgcn_fdot2)
__device__ inline float dot_qk(const uint2& k, const uint2& q, float c) {
  c = __builtin_amdgcn_fdot2(__builtin_bit_cast(h2v, k.x), __builtin_bit_cast(h2v, q.x), c, false);
  c = __builtin_amdgcn_fdot2(__builtin_bit_cast(h2v, k.y), __builtin_bit_cast(h2v, q.y), c, false);
  return c;
}
__device__ inline float dot_qk(const uint4& k, const uint4& q, float c) {
  c = __builtin_amdgcn_fdot2(__builtin_bit_cast(h2v, k.x), __builtin_bit_cast(h2v, q.x), c, false);
  c = __builtin_amdgcn_fdot2(__builtin_bit_cast(h2v, k.y), __builtin_bit_cast(h2v, q.y), c, false);
  c = __builtin_amdgcn_fdot2(__builtin_bit_cast(h2v, k.z), __builtin_bit_cast(h2v, q.z), c, false);
  c = __builtin_amdgcn_fdot2(__builtin_bit_cast(h2v, k.w), __builtin_bit_cast(h2v, q.w), c, false);
  return c;
}
#else
__device__ inline float dot_qk(const uint2& k, const uint2& q, float c) {
  float4 kk[1], qq[1];
  cvt_kv(k, kk); cvt_kv(q, qq);
  return c + qq[0].x * kk[0].x + qq[0].y * kk[0].y + qq[0].z * kk[0].z + qq[0].w * kk[0].w;
}
__device__ inline float dot_qk(const uint4& k, const uint4& q, float c) {
  float4 kk[2], qq[2];
  cvt_kv(k, kk); cvt_kv(q, qq);
  c += qq[0].x * kk[0].x + qq[0].y * kk[0].y + qq[0].z * kk[0].z + qq[0].w * kk[0].w;
  c += qq[1].x * kk[1].x + qq[1].y * kk[1].y + qq[1].z * kk[1].z + qq[1].w * kk[1].w;
  return c;
}
#endif

// ---------------------------------------------------------------------------
// MFMA GEMM: [Q|G|K|V|S] = A[M,K]_f16 @ Wp_f16 + bias_f32.
// For DOUT==64 layers, the KV output is stored INTERLEAVED per (head,t16):
// 16-half blocks [K d..d+3 | V d..d+3], so the edge kernel gathers K and V
// with ONE dwordx4 per edge instead of two loads 512B apart.
// ---------------------------------------------------------------------------
template <int K, int HD, int DOUT>
__global__ __launch_bounds__(256) void gemm_mfma(
    const __half* __restrict__ A, const __half* __restrict__ Wp,
    const float* __restrict__ bias, __half* __restrict__ QS,
    __half* __restrict__ KV, int M) {
  constexpr int QSS = HD + 64 + DOUT;
  constexpr int KVS = 2 * HD;
  constexpr int KS = K / 32;
  constexpr int NV = DOUT / 64;
  __shared__ __half st[64][72];
  const int tid = threadIdx.x;
  const int wave = tid >> 6, lane = tid & 63;
  const int quad = lane >> 4, n16 = lane & 15;
  const int row0 = blockIdx.y * 64;
  const int col0 = blockIdx.x * 64;
  const int nblk0 = blockIdx.x * 4;

  const int arow = min(row0 + wave * 16 + n16, M - 1);
  half8 afrag[KS];
#pragma unroll
  for (int s = 0; s < KS; ++s)
    afrag[s] = *reinterpret_cast<const half8*>(A + (size_t)arow * K + s * 32 + quad * 8);

  floatx4 acc[4];
#pragma unroll
  for (int t = 0; t < 4; ++t) {
    acc[t] = (floatx4){0.f, 0.f, 0.f, 0.f};
#pragma unroll
    for (int s = 0; s < KS; ++s) {
      half8 bf = *reinterpret_cast<const half8*>(
          Wp + (((size_t)(nblk0 + t) * KS + s) * 64 + lane) * 8);
      acc[t] = __builtin_amdgcn_mfma_f32_16x16x32_f16(afrag[s], bf, acc[t], 0, 0, 0);
    }
  }

#pragma unroll
  for (int t = 0; t < 4; ++t) {
    float bv = bias[col0 + t * 16 + n16];
#pragma unroll
    for (int r = 0; r < 4; ++r)
      st[wave * 16 + quad * 4 + r][t * 16 + n16] = __float2half(acc[t][r] + bv);
  }
  __syncthreads();

  __half* dp;
  int colb, stride;
  bool kvreg = false;
  if (col0 < HD + 64) {
    dp = QS; colb = col0; stride = QSS;
  } else if (col0 < 3 * HD + 64) {
    dp = KV; colb = col0 - HD - 64; stride = KVS; kvreg = true;
  } else {
    dp = QS; colb = HD + 64 + (col0 - 3 * HD - 64); stride = QSS;
  }
  for (int c = tid; c < 512; c += 256) {
    int r = c >> 3, seg = c & 7;
    int row = row0 + r;
    if (row >= M) continue;
    if (NV == 1 && kvreg) {
      // interleaved scatter: 8 halves -> two 4-half sub-blocks
      int dfull = colb + seg * 8;            // 0..2*HD
      bool isK = dfull < HD;
      int dd = isK ? dfull : dfull - HD;     // col within K or V
      int hh = dd >> 6, d0 = dd & 63;        // head, in-head col (mult of 8)
      int o = hh * 128 + 2 * d0 + (isK ? 0 : 4);
      uint4 w = *reinterpret_cast<const uint4*>(&st[r][seg * 8]);
      *reinterpret_cast<uint2*>(dp + (size_t)row * stride + o) = make_uint2(w.x, w.y);
      *reinterpret_cast<uint2*>(dp + (size_t)row * stride + o + 8) = make_uint2(w.z, w.w);
    } else {
      *reinterpret_cast<uint4*>(dp + (size_t)row * stride + colb + seg * 8) =
          *reinterpret_cast<const uint4*>(&st[r][seg * 8]);
    }
  }
}

// ---------------------------------------------------------------------------
// Pack weights into B-fragment order (f16), with fused G columns.
// ---------------------------------------------------------------------------
__device__ inline void pack_layer(int i, int K, int HD, int DOUT, float scale,
                                  const float* wq, const float* wk,
                                  const float* wv, const float* wsk,
                                  const float* we, const float* bq,
                                  const float* bk, const float* bv,
                                  const float* bs, __half* Wp, float* bcat) {
  const int W = 3 * HD + DOUT + 64;
  const int KS = K / 32;
  if (i < K * W) {
    int j = i & 7, lane = (i >> 3) & 63, fs = i >> 9;
    int nblk = fs / KS, s = fs - nblk * KS;
    int quad = lane >> 4, n = lane & 15;
    int k = s * 32 + quad * 8 + j, c = nblk * 16 + n;
    float v;
    if (c < HD) {
      v = wq[k * HD + c] * scale;
    } else if (c < HD + 64) {
      int gi = c - HD, hh = gi >> 4, d = gi & 15;
      float a = 0.f;
      for (int cc = 0; cc < DOUT; ++cc)
        a += wq[k * HD + hh * DOUT + cc] * we[d * HD + hh * DOUT + cc];
      v = a * scale;
    } else if (c < 2 * HD + 64) {
      v = wk[k * HD + (c - HD - 64)];
    } else if (c < 3 * HD + 64) {
      v = wv[k * HD + (c - 2 * HD - 64)];
    } else {
      v = wsk[k * DOUT + (c - 3 * HD - 64)];
    }
    Wp[i] = __float2half(v);
  } else {
    int c = i - K * W;
    float v;
    if (c < HD) {
      v = bq[c] * scale;
    } else if (c < HD + 64) {
      int gi = c - HD, hh = gi >> 4, d = gi & 15;
      float a = 0.f;
      for (int cc = 0; cc < DOUT; ++cc)
        a += bq[hh * DOUT + cc] * we[d * HD + hh * DOUT + cc];
      v = a * scale;
    } else if (c < 2 * HD + 64) {
      v = bk[c - HD - 64];
    } else if (c < 3 * HD + 64) {
      v = bv[c - 2 * HD - 64];
    } else {
      v = bs[c - 3 * HD - 64];
    }
    bcat[c] = v;
  }
}

#define T1 115584            // 128*896 + 896
#define T2 227904            // T1 + 64*1728 + 1728
#define T3 343488            // T2 + 128*896 + 896
#define TCONV (N_NODES * 32) // x float4 count
#define TTOT (T3 + TCONV)

__global__ void pack_all(
    const float* wq1, const float* wk1, const float* wv1, const float* ws1,
    const float* we1, const float* bq1, const float* bk1, const float* bv1,
    const float* bs1,
    const float* wq2, const float* wk2, const float* wv2, const float* ws2,
    const float* we2, const float* bq2, const float* bk2, const float* bv2,
    const float* bs2,
    const float* wq3, const float* wk3, const float* wv3, const float* ws3,
    const float* we3, const float* bq3, const float* bk3, const float* bv3,
    const float* bs3,
    __half* W1, float* b1, __half* W2, float* b2, __half* W3, float* b3,
    const float* x, __half* x16) {
  const float SC1 = 0.125f, SC2 = 0.08838834764831845f;
  for (int i = blockIdx.x * blockDim.x + threadIdx.x; i < TTOT;
       i += gridDim.x * blockDim.x) {
    if (i < T1)
      pack_layer(i, 128, 256, 64, SC1, wq1, wk1, wv1, ws1, we1, bq1, bk1, bv1, bs1, W1, b1);
    else if (i < T2)
      pack_layer(i - T1, 64, 512, 128, SC2, wq2, wk2, wv2, ws2, we2, bq2, bk2, bv2, bs2, W2, b2);
    else if (i < T3)
      pack_layer(i - T2, 128, 256, 64, SC1, wq3, wk3, wv3, ws3, we3, bq3, bk3, bv3, bs3, W3, b3);
    else {
      int k = i - T3;
      float4 v = reinterpret_cast<const float4*>(x)[k];
      __half2* o = reinterpret_cast<__half2*>(x16) + 2 * k;
      o[0] = __floats2half2_rn(v.x, v.y);
      o[1] = __floats2half2_rn(v.z, v.w);
    }
  }
}

// ---------------------------------------------------------------------------
// CSR build over dst
// ---------------------------------------------------------------------------
__global__ void count_dst(const int* __restrict__ dst, int* __restrict__ cnt) {
  int e = blockIdx.x * blockDim.x + threadIdx.x;
  if (e < N_EDGES) atomicAdd(&cnt[dst[e]], 1);
}

// Fused: exclusive scan of degrees -> offs, AND degree-descending counting
// sort of nodes -> perm (schedules heavy nodes first in edge_attn).
__global__ __launch_bounds__(1024) void scan_offs(const int* __restrict__ cnt,
                                                  int* __restrict__ offs,
                                                  int* __restrict__ perm) {
  __shared__ int part[1024];
  __shared__ int hist[256], hstart[256], hcur[256];
  const int t = threadIdx.x;
  const int chunk = (N_NODES + 1023) / 1024;
  const int b = t * chunk;
  const int e = min(N_NODES, b + chunk);
  if (t < 256) { hist[t] = 0; hcur[t] = 0; }
  __syncthreads();
  int s = 0;
  for (int i = b; i < e; ++i) {
    int d = cnt[i];
    s += d;
    atomicAdd(&hist[min(d, 255)], 1);
  }
  part[t] = s;
  __syncthreads();
  for (int off = 1; off < 1024; off <<= 1) {
    int v = (t >= off) ? part[t - off] : 0;
    __syncthreads();
    part[t] += v;
    __syncthreads();
  }
  if (t == 0) {
    int acc = 0;
    for (int bk = 255; bk >= 0; --bk) { hstart[bk] = acc; acc += hist[bk]; }
    offs[N_NODES] = part[1023];
  }
  __syncthreads();
  int pre = (t == 0) ? 0 : part[t - 1];
  for (int i = b; i < e; ++i) {
    offs[i] = pre;
    int d = cnt[i];
    pre += d;
    int bkt = min(d, 255);
    int pos = hstart[bkt] + atomicAdd(&hcur[bkt], 1);
    perm[pos] = i;
  }
}

__global__ void scatter_csr(const int* __restrict__ src, const int* __restrict__ dst,
                            const float* __restrict__ edge_attr,
                            const int* __restrict__ offs, int* __restrict__ cursor,
                            int* __restrict__ csr_src, float* __restrict__ csr_ea) {
  int e = blockIdx.x * blockDim.x + threadIdx.x;
  if (e < N_EDGES) {
    int d = dst[e];
    int pos = offs[d] + atomicAdd(&cursor[d], 1);
    csr_src[pos] = src[e];
    float4* o4 = reinterpret_cast<float4*>(csr_ea + (size_t)pos * 16);
    const float4* s4 = reinterpret_cast<const float4*>(edge_attr + (size_t)e * 16);
    o4[0] = s4[0]; o4[1] = s4[1]; o4[2] = s4[2]; o4[3] = s4[3];
  }
}

// ---------------------------------------------------------------------------
// Fused edge kernel. r3 structure (1 node/wave, depth-3 pipeline, hoisted
// index fetch) + fdot2 Q.K + fused K|V single-load for NV==1 layers (the
// gemm stores layer-1/3 KV interleaved: one dwordx4 per edge fetches both).
// ---------------------------------------------------------------------------
template <int DOUT, bool W32>
__global__ __launch_bounds__(128) void edge_attn(
    const __half* __restrict__ QS, const __half* __restrict__ KV,
    const float* __restrict__ we, const int* __restrict__ csr_src,
    const float* __restrict__ csr_ea, const int* __restrict__ offs,
    const int* __restrict__ perm, float* __restrict__ out,
    __half* __restrict__ out16) {
  constexpr int HD = 4 * DOUT;
  constexpr int QSS = HD + 64 + DOUT;
  constexpr int KVS = 2 * HD;
  constexpr int NV = DOUT / 64;
  using KWT = typename KW<NV>::T;

  const int lane = threadIdx.x & 63;
  const int h = lane >> 4, t16 = lane & 15;
  const int n = perm[blockIdx.x * 2 + (threadIdx.x >> 6)];  // N_NODES % 2 == 0
  const int c0 = t16 * 4 * NV;
  // per-lane byte offset into a node's KV row (same formula both layouts)
  const int kvoff = h * 128 + t16 * 8;

  const __half* base = QS + (size_t)n * QSS;
  KWT qw = *reinterpret_cast<const KWT*>(base + h * DOUT + c0);
  float4 acc[NV];
#pragma unroll
  for (int v = 0; v < NV; ++v) acc[v] = make_float4(0.f, 0.f, 0.f, 0.f);
  const float g = __half2float(base[HD + h * 16 + t16]);  // pre-scaled G

  float lsum = 0.f, tacc = 0.f;

  const int s0 = offs[n], s1 = offs[n + 1];

  float eaA[4], eaB[4], eaC[4];
  // NV==1: kr holds the fused [K|V] dwordx4; vr unused (elided by compiler).
  uint4 krA[4], vrA[4], krB[4], vrB[4], krC[4], vrC[4];

  for (int cb = s0; cb < s1; cb += 64) {
    const int m = min(64, s1 - cb);
    const int idx = csr_src[cb + min(lane, m - 1)];  // coalesced, once/chunk
    const int ng = m >> 2;

    auto load_grp = [&](int gb, float (&ea)[4], uint4 (&kr)[4], uint4 (&vr)[4]) {
      const int bi = cb + gb;
#pragma unroll
      for (int j = 0; j < 4; ++j) ea[j] = csr_ea[(size_t)(bi + j) * 16 + t16];
#pragma unroll
      for (int j = 0; j < 4; ++j) {
        int sj = __shfl(idx, gb + j);
        const __half* rb = KV + (size_t)sj * KVS + kvoff;
        kr[j] = *reinterpret_cast<const uint4*>(rb);
        if (NV == 2) vr[j] = *reinterpret_cast<const uint4*>(rb + HD);
      }
    };

    auto compute_grp = [&](float (&ea)[4], uint4 (&kr)[4], uint4 (&vr)[4]) {
      float a[4];
#pragma unroll
      for (int j = 0; j < 4; ++j) {
        if (NV == 1)
          a[j] = dot_qk(make_uint2(kr[j].x, kr[j].y),
                        *reinterpret_cast<const uint2*>(&qw), ea[j] * g);
        else
          a[j] = dot_qk(*reinterpret_cast<const uint4*>(&kr[j]),
                        *reinterpret_cast<const uint4*>(&qw), ea[j] * g);
      }
#pragma unroll
      for (int j = 0; j < 4; ++j) {
        a[j] += __shfl_xor(a[j], 1);
        a[j] += __shfl_xor(a[j], 2);
        a[j] += __shfl_xor(a[j], 4);
        a[j] += __shfl_xor(a[j], 8);
      }
      float p0 = __expf(a[0]), p1 = __expf(a[1]);
      float p2 = __expf(a[2]), p3 = __expf(a[3]);
      lsum += p0 + p1 + p2 + p3;
      tacc += p0 * ea[0] + p1 * ea[1] + p2 * ea[2] + p3 * ea[3];
      float pj[4] = {p0, p1, p2, p3};
#pragma unroll
      for (int j = 0; j < 4; ++j) {
        float4 vv[NV];
        if (NV == 1)
          cvt_kv(make_uint2(kr[j].z, kr[j].w), vv);
        else
          cvt_kv(vr[j], vv);
#pragma unroll
        for (int v = 0; v < NV; ++v) {
          acc[v].x += pj[j] * vv[v].x;
          acc[v].y += pj[j] * vv[v].y;
          acc[v].z += pj[j] * vv[v].z;
          acc[v].w += pj[j] * vv[v].w;
        }
      }
    };

    if (ng) {
      load_grp(0, eaA, krA, vrA);
      if (ng > 1) load_grp(4, eaB, krB, vrB);
      int gi = 0;
      for (;;) {
        if (gi + 2 < ng) load_grp((gi + 2) * 4, eaC, krC, vrC);
        compute_grp(eaA, krA, vrA);
        if (++gi >= ng) break;
        if (gi + 2 < ng) load_grp((gi + 2) * 4, eaA, krA, vrA);
        compute_grp(eaB, krB, vrB);
        if (++gi >= ng) break;
        if (gi + 2 < ng) load_grp((gi + 2) * 4, eaB, krB, vrB);
        compute_grp(eaC, krC, vrC);
        if (++gi >= ng) break;
      }
    }

    // tail (m & 3 edges)
    for (int e = ng * 4; e < m; ++e) {
      int sj = __shfl(idx, e);
      float ea0 = csr_ea[(size_t)(cb + e) * 16 + t16];
      const __half* rb = KV + (size_t)sj * KVS + kvoff;
      uint4 kw = *reinterpret_cast<const uint4*>(rb);
      float a;
      float4 vv[NV];
      if (NV == 1) {
        a = dot_qk(make_uint2(kw.x, kw.y),
                   *reinterpret_cast<const uint2*>(&qw), ea0 * g);
        cvt_kv(make_uint2(kw.z, kw.w), vv);
      } else {
        uint4 vw = *reinterpret_cast<const uint4*>(rb + HD);
        a = dot_qk(kw, *reinterpret_cast<const uint4*>(&qw), ea0 * g);
        cvt_kv(vw, vv);
      }
      a += __shfl_xor(a, 1);
      a += __shfl_xor(a, 2);
      a += __shfl_xor(a, 4);
      a += __shfl_xor(a, 8);
      float p = __expf(a);
      lsum += p;
      tacc += p * ea0;
#pragma unroll
      for (int v = 0; v < NV; ++v) {
        acc[v].x += p * vv[v].x;
        acc[v].y += p * vv[v].y;
        acc[v].z += p * vv[v].z;
        acc[v].w += p * vv[v].w;
      }
    }
  }

  // epilogue: normalize, add (sum attn*ea)@we, head mean, skip, ELU
  float invl = (lsum > 0.f) ? 1.f / lsum : 0.f;
  float tn = tacc * invl;
  float4 val[NV];
#pragma unroll
  for (int v = 0; v < NV; ++v) {
    val[v].x = acc[v].x * invl; val[v].y = acc[v].y * invl;
    val[v].z = acc[v].z * invl; val[v].w = acc[v].w * invl;
  }
#pragma unroll
  for (int d = 0; d < 16; ++d) {
    float td = __shfl(tn, (lane & 48) | d);
    const float* wb = we + d * HD + h * DOUT + c0;
#pragma unroll
    for (int v = 0; v < NV; ++v) {
      float4 w4 = *reinterpret_cast<const float4*>(wb + 4 * v);
      val[v].x += td * w4.x; val[v].y += td * w4.y;
      val[v].z += td * w4.z; val[v].w += td * w4.w;
    }
  }
#pragma unroll
  for (int v = 0; v < NV; ++v) {
    val[v].x += __shfl_xor(val[v].x, 16); val[v].x += __shfl_xor(val[v].x, 32);
    val[v].y += __shfl_xor(val[v].y, 16); val[v].y += __shfl_xor(val[v].y, 32);
    val[v].z += __shfl_xor(val[v].z, 16); val[v].z += __shfl_xor(val[v].z, 32);
    val[v].w += __shfl_xor(val[v].w, 16); val[v].w += __shfl_xor(val[v].w, 32);
  }
  if (h == 0) {
    KWT sw = *reinterpret_cast<const KWT*>(base + HD + 64 + c0);
    float4 sk[NV];
    cvt_kv(sw, sk);
#pragma unroll
    for (int v = 0; v < NV; ++v) {
      float4 o;
      o.x = 0.25f * val[v].x + sk[v].x;
      o.y = 0.25f * val[v].y + sk[v].y;
      o.z = 0.25f * val[v].z + sk[v].z;
      o.w = 0.25f * val[v].w + sk[v].w;
      o.x = (o.x > 0.f) ? o.x : expm1f(o.x);
      o.y = (o.y > 0.f) ? o.y : expm1f(o.y);
      o.z = (o.z > 0.f) ? o.z : expm1f(o.z);
      o.w = (o.w > 0.f) ? o.w : expm1f(o.w);
      if (W32)
        *reinterpret_cast<float4*>(out + (size_t)n * DOUT + c0 + 4 * v) = o;
      __half2* o16 = reinterpret_cast<__half2*>(out16 + (size_t)n * DOUT + c0 + 4 * v);
      o16[0] = __floats2half2_rn(o.x, o.y);
      o16[1] = __floats2half2_rn(o.z, o.w);
    }
  }
}

// ---------------------------------------------------------------------------
// Global mean pool (batch sorted -> contiguous per-graph ranges)
// ---------------------------------------------------------------------------
__device__ inline int lower_bound(const int* b, int n, int v) {
  int lo = 0, hi = n;
  while (lo < hi) {
    int mid = (lo + hi) >> 1;
    if (b[mid] < v) lo = mid + 1; else hi = mid;
  }
  return lo;
}

__global__ __launch_bounds__(256) void pool_all(const float* __restrict__ h,
                                                const int* __restrict__ batch,
                                                float* __restrict__ out) {
  const int g = blockIdx.x;
  const int start = lower_bound(batch, N_NODES, g);
  const int end = lower_bound(batch, N_NODES, g + 1);
  const int c = threadIdx.x & 63, j = threadIdx.x >> 6;
  float s = 0.f;
  for (int n = start + j; n < end; n += 4) s += h[(size_t)n * 64 + c];
  __shared__ float red[4][64];
  red[j][c] = s;
  __syncthreads();
  if (j == 0) {
    float tot = red[0][c] + red[1][c] + red[2][c] + red[3][c];
    out[g * 64 + c] = tot / (float)max(end - start, 1);
  }
}

// ---------------------------------------------------------------------------
extern "C" void kernel_launch(void* const* d_in, const int* in_sizes, int n_in,
                              void* d_out, int out_size, void* d_ws, size_t ws_size,
                              hipStream_t stream) {
  const float* x = (const float*)d_in[0];
  const int* edge_index = (const int*)d_in[1];
  const float* edge_attr = (const float*)d_in[2];
  const int* batch = (const int*)d_in[3];
  const int* srcp = edge_index;
  const int* dstp = edge_index + N_EDGES;

  const bool dict_order = in_sizes[5] > 1024;
  const float *wq[3], *wk[3], *wv[3], *wep[3], *wsk[3], *bq[3], *bk[3], *bv[3], *bs[3];
  for (int L = 0; L < 3; ++L) {
    int b = 4 + L * 9;
    if (dict_order) {
      wq[L] = (const float*)d_in[b + 0];
      wk[L] = (const float*)d_in[b + 1];
      wv[L] = (const float*)d_in[b + 2];
      wep[L] = (const float*)d_in[b + 3];
      wsk[L] = (const float*)d_in[b + 4];
      bq[L] = (const float*)d_in[b + 5];
      bk[L] = (const float*)d_in[b + 6];
      bv[L] = (const float*)d_in[b + 7];
      bs[L] = (const float*)d_in[b + 8];
    } else {
      wq[L] = (const float*)d_in[b + 0];
      bq[L] = (const float*)d_in[b + 1];
      wk[L] = (const float*)d_in[b + 2];
      bk[L] = (const float*)d_in[b + 3];
      wv[L] = (const float*)d_in[b + 4];
      bv[L] = (const float*)d_in[b + 5];
      wep[L] = (const float*)d_in[b + 6];
      wsk[L] = (const float*)d_in[b + 7];
      bs[L] = (const float*)d_in[b + 8];
    }
  }

  // Workspace carve (bytes).
  char* p = (char*)d_ws;
  __half* qs = (__half*)p;    p += (size_t)N_NODES * 704 * 2;   // Q|G|S f16 (max L2)
  __half* kv = (__half*)p;    p += (size_t)N_NODES * 1024 * 2;  // K|V f16 (max L2)
  float* h1 = (float*)p;      p += (size_t)N_NODES * 64 * 4;
  __half* x16 = (__half*)p;   p += (size_t)N_NODES * 128 * 2;
  __half* h16 = (__half*)p;   p += (size_t)N_NODES * 128 * 2;
  __half* W1 = (__half*)p;    p += 128 * 896 * 2;
  __half* W2 = (__half*)p;    p += 64 * 1728 * 2;
  __half* W3 = (__half*)p;    p += 128 * 896 * 2;
  float* b1 = (float*)p;      p += 896 * 4;
  float* b2 = (float*)p;      p += 1728 * 4;
  float* b3 = (float*)p;      p += 896 * 4;
  float* csr_ea = (float*)p;  p += (size_t)N_EDGES * 16 * 4;
  int* cnt = (int*)p;         p += N_NODES * 4;
  int* cursor = (int*)p;      p += N_NODES * 4;
  int* offs = (int*)p;        p += (N_NODES + 1) * 4;
  int* perm = (int*)p;        p += N_NODES * 4;
  int* csr_src = (int*)p;     p += N_EDGES * 4;

  // ---- pack weights (f16 frag order, fused G cols) + x->f16 (1 launch) ----
  pack_all<<<1024, 256, 0, stream>>>(
      wq[0], wk[0], wv[0], wsk[0], wep[0], bq[0], bk[0], bv[0], bs[0],
      wq[1], wk[1], wv[1], wsk[1], wep[1], bq[1], bk[1], bv[1], bs[1],
      wq[2], wk[2], wv[2], wsk[2], wep[2], bq[2], bk[2], bv[2], bs[2],
      W1, b1, W2, b2, W3, b3, x, x16);

  // ---- CSR build over dst + degree-sorted scheduling permutation ----
  hipMemsetAsync(cnt, 0, 2 * N_NODES * sizeof(int), stream);  // cnt + cursor
  count_dst<<<(N_EDGES + 255) / 256, 256, 0, stream>>>(dstp, cnt);
  scan_offs<<<1, 1024, 0, stream>>>(cnt, offs, perm);
  scatter_csr<<<(N_EDGES + 255) / 256, 256, 0, stream>>>(srcp, dstp, edge_attr,
                                                         offs, cursor, csr_src, csr_ea);

  const int MT = (N_NODES + 63) / 64;
  // ---- layer 1: K=128, HD=256, DOUT=64 ----
  gemm_mfma<128, 256, 64><<<dim3(896 / 64, MT), 256, 0, stream>>>(x16, W1, b1, qs,
                                                                  kv, N_NODES);
  edge_attn<64, false><<<N_NODES / 2, 128, 0, stream>>>(qs, kv, wep[0], csr_src,
                                                        csr_ea, offs, perm, h1, h16);
  // ---- layer 2: K=64, HD=512, DOUT=128 ----
  gemm_mfma<64, 512, 128><<<dim3(1728 / 64, MT), 256, 0, stream>>>(h16, W2, b2, qs,
                                                                   kv, N_NODES);
  edge_attn<128, false><<<N_NODES / 2, 128, 0, stream>>>(qs, kv, wep[1], csr_src,
                                                         csr_ea, offs, perm, h1, h16);
  // ---- layer 3: K=128, HD=256, DOUT=64 ----
  gemm_mfma<128, 256, 64><<<dim3(896 / 64, MT), 256, 0, stream>>>(h16, W3, b3, qs,
                                                                  kv, N_NODES);
  edge_attn<64, true><<<N_NODES / 2, 128, 0, stream>>>(qs, kv, wep[2], csr_src,
                                                       csr_ea, offs, perm, h1, x16);

  // ---- global mean pool ----
  pool_all<<<N_GRAPHS, 256, 0, stream>>>(h1, batch, (float*)d_out);
}

// Round 7
// 325.335 us; speedup vs baseline: 1.0768x; 1.0113x over previous
//
#include <hip/hip_runtime.h>
#include <hip/hip_fp16.h>
#include <math.h>

#define N_NODES 10000
#define N_EDGES 160000
#define N_GRAPHS 64

using half8 = __attribute__((ext_vector_type(8))) _Float16;
using floatx4 = __attribute__((ext_vector_type(4))) float;
using h2v = __attribute__((ext_vector_type(2))) _Float16;

// raw f16 fragment word: 4 halfs (NV=1) or 8 halfs (NV=2)
template <int NV> struct KW;
template <> struct KW<1> { using T = uint2; };
template <> struct KW<2> { using T = uint4; };

__device__ inline void cvt_kv(const uint2& w, float4* dst) {
  float2 a = __half22float2(*reinterpret_cast<const __half2*>(&w.x));
  float2 b = __half22float2(*reinterpret_cast<const __half2*>(&w.y));
  dst[0] = make_float4(a.x, a.y, b.x, b.y);
}
__device__ inline void cvt_kv(const uint4& w, float4* dst) {
  float2 a = __half22float2(*reinterpret_cast<const __half2*>(&w.x));
  float2 b = __half22float2(*reinterpret_cast<const __half2*>(&w.y));
  float2 c = __half22float2(*reinterpret_cast<const __half2*>(&w.z));
  float2 d = __half22float2(*reinterpret_cast<const __half2*>(&w.w));
  dst[0] = make_float4(a.x, a.y, b.x, b.y);
  dst[1] = make_float4(c.x, c.y, d.x, d.y);
}

// Q.K dot in f16 via v_dot2_f32_f16 (f32 accumulate) — kills the K-side cvt.
#if __has_builtin(__builtin_amdgcn_fdot2)
__device__ inline float dot_qk(const uint2& k, const uint2& q, float c) {
  c = __builtin_amdgcn_fdot2(__builtin_bit_cast(h2v, k.x), __builtin_bit_cast(h2v, q.x), c, false);
  c = __builtin_amdgcn_fdot2(__builtin_bit_cast(h2v, k.y), __builtin_bit_cast(h2v, q.y), c, false);
  return c;
}
__device__ inline float dot_qk(const uint4& k, const uint4& q, float c) {
  c = __builtin_amdgcn_fdot2(__builtin_bit_cast(h2v, k.x), __builtin_bit_cast(h2v, q.x), c, false);
  c = __builtin_amdgcn_fdot2(__builtin_bit_cast(h2v, k.y), __builtin_bit_cast(h2v, q.y), c, false);
  c = __builtin_amdgcn_fdot2(__builtin_bit_cast(h2v, k.z), __builtin_bit_cast(h2v, q.z), c, false);
  c = __builtin_amdgcn_fdot2(__builtin_bit_cast(h2v, k.w), __builtin_bit_cast(h2v, q.w), c, false);
  return c;
}
#else
__device__ inline float dot_qk(const uint2& k, const uint2& q, float c) {
  float4 kk[1], qq[1];
  cvt_kv(k, kk); cvt_kv(q, qq);
  return c + qq[0].x * kk[0].x + qq[0].y * kk[0].y + qq[0].z * kk[0].z + qq[0].w * kk[0].w;
}
__device__ inline float dot_qk(const uint4& k, const uint4& q, float c) {
  float4 kk[2], qq[2];
  cvt_kv(k, kk); cvt_kv(q, qq);
  c += qq[0].x * kk[0].x + qq[0].y * kk[0].y + qq[0].z * kk[0].z + qq[0].w * kk[0].w;
  c += qq[1].x * kk[1].x + qq[1].y * kk[1].y + qq[1].z * kk[1].z + qq[1].w * kk[1].w;
  return c;
}
#endif

__device__ inline int lower_bound(const int* b, int n, int v) {
  int lo = 0, hi = n;
  while (lo < hi) {
    int mid = (lo + hi) >> 1;
    if (b[mid] < v) lo = mid + 1; else hi = mid;
  }
  return lo;
}

// ---------------------------------------------------------------------------
// MFMA GEMM: [Q|G|K|V|S] = A[M,K]_f16 @ Wp_f16 + bias_f32.
// For DOUT==64 layers, the KV output is stored INTERLEAVED per (head,t16):
// 16-half blocks [K d..d+3 | V d..d+3] -> edge kernel gathers K+V in one
// dwordx4.
// ---------------------------------------------------------------------------
template <int K, int HD, int DOUT>
__global__ __launch_bounds__(256) void gemm_mfma(
    const __half* __restrict__ A, const __half* __restrict__ Wp,
    const float* __restrict__ bias, __half* __restrict__ QS,
    __half* __restrict__ KV, int M) {
  constexpr int QSS = HD + 64 + DOUT;
  constexpr int KVS = 2 * HD;
  constexpr int KS = K / 32;
  constexpr int NV = DOUT / 64;
  __shared__ __half st[64][72];
  const int tid = threadIdx.x;
  const int wave = tid >> 6, lane = tid & 63;
  const int quad = lane >> 4, n16 = lane & 15;
  const int row0 = blockIdx.y * 64;
  const int col0 = blockIdx.x * 64;
  const int nblk0 = blockIdx.x * 4;

  const int arow = min(row0 + wave * 16 + n16, M - 1);
  half8 afrag[KS];
#pragma unroll
  for (int s = 0; s < KS; ++s)
    afrag[s] = *reinterpret_cast<const half8*>(A + (size_t)arow * K + s * 32 + quad * 8);

  floatx4 acc[4];
#pragma unroll
  for (int t = 0; t < 4; ++t) {
    acc[t] = (floatx4){0.f, 0.f, 0.f, 0.f};
#pragma unroll
    for (int s = 0; s < KS; ++s) {
      half8 bf = *reinterpret_cast<const half8*>(
          Wp + (((size_t)(nblk0 + t) * KS + s) * 64 + lane) * 8);
      acc[t] = __builtin_amdgcn_mfma_f32_16x16x32_f16(afrag[s], bf, acc[t], 0, 0, 0);
    }
  }

#pragma unroll
  for (int t = 0; t < 4; ++t) {
    float bv = bias[col0 + t * 16 + n16];
#pragma unroll
    for (int r = 0; r < 4; ++r)
      st[wave * 16 + quad * 4 + r][t * 16 + n16] = __float2half(acc[t][r] + bv);
  }
  __syncthreads();

  __half* dp;
  int colb, stride;
  bool kvreg = false;
  if (col0 < HD + 64) {
    dp = QS; colb = col0; stride = QSS;
  } else if (col0 < 3 * HD + 64) {
    dp = KV; colb = col0 - HD - 64; stride = KVS; kvreg = true;
  } else {
    dp = QS; colb = HD + 64 + (col0 - 3 * HD - 64); stride = QSS;
  }
  for (int c = tid; c < 512; c += 256) {
    int r = c >> 3, seg = c & 7;
    int row = row0 + r;
    if (row >= M) continue;
    if (NV == 1 && kvreg) {
      int dfull = colb + seg * 8;
      bool isK = dfull < HD;
      int dd = isK ? dfull : dfull - HD;
      int hh = dd >> 6, d0 = dd & 63;
      int o = hh * 128 + 2 * d0 + (isK ? 0 : 4);
      uint4 w = *reinterpret_cast<const uint4*>(&st[r][seg * 8]);
      *reinterpret_cast<uint2*>(dp + (size_t)row * stride + o) = make_uint2(w.x, w.y);
      *reinterpret_cast<uint2*>(dp + (size_t)row * stride + o + 8) = make_uint2(w.z, w.w);
    } else {
      *reinterpret_cast<uint4*>(dp + (size_t)row * stride + colb + seg * 8) =
          *reinterpret_cast<const uint4*>(&st[r][seg * 8]);
    }
  }
}

// ---------------------------------------------------------------------------
// Pack weights into B-fragment order (f16), with fused G columns.
// ---------------------------------------------------------------------------
__device__ inline void pack_layer(int i, int K, int HD, int DOUT, float scale,
                                  const float* wq, const float* wk,
                                  const float* wv, const float* wsk,
                                  const float* we, const float* bq,
                                  const float* bk, const float* bv,
                                  const float* bs, __half* Wp, float* bcat) {
  const int W = 3 * HD + DOUT + 64;
  const int KS = K / 32;
  if (i < K * W) {
    int j = i & 7, lane = (i >> 3) & 63, fs = i >> 9;
    int nblk = fs / KS, s = fs - nblk * KS;
    int quad = lane >> 4, n = lane & 15;
    int k = s * 32 + quad * 8 + j, c = nblk * 16 + n;
    float v;
    if (c < HD) {
      v = wq[k * HD + c] * scale;
    } else if (c < HD + 64) {
      int gi = c - HD, hh = gi >> 4, d = gi & 15;
      float a = 0.f;
      for (int cc = 0; cc < DOUT; ++cc)
        a += wq[k * HD + hh * DOUT + cc] * we[d * HD + hh * DOUT + cc];
      v = a * scale;
    } else if (c < 2 * HD + 64) {
      v = wk[k * HD + (c - HD - 64)];
    } else if (c < 3 * HD + 64) {
      v = wv[k * HD + (c - 2 * HD - 64)];
    } else {
      v = wsk[k * DOUT + (c - 3 * HD - 64)];
    }
    Wp[i] = __float2half(v);
  } else {
    int c = i - K * W;
    float v;
    if (c < HD) {
      v = bq[c] * scale;
    } else if (c < HD + 64) {
      int gi = c - HD, hh = gi >> 4, d = gi & 15;
      float a = 0.f;
      for (int cc = 0; cc < DOUT; ++cc)
        a += bq[hh * DOUT + cc] * we[d * HD + hh * DOUT + cc];
      v = a * scale;
    } else if (c < 2 * HD + 64) {
      v = bk[c - HD - 64];
    } else if (c < 3 * HD + 64) {
      v = bv[c - 2 * HD - 64];
    } else {
      v = bs[c - 3 * HD - 64];
    }
    bcat[c] = v;
  }
}

#define T1 115584            // 128*896 + 896
#define T2 227904            // T1 + 64*1728 + 1728
#define T3 343488            // T2 + 128*896 + 896
#define TCONV (N_NODES * 32) // x float4 count
#define TTOT (T3 + TCONV)
#define NZERO (2 * N_NODES + N_GRAPHS * 64)  // cnt+cursor ints, d_out floats

__global__ void pack_all(
    const float* wq1, const float* wk1, const float* wv1, const float* ws1,
    const float* we1, const float* bq1, const float* bk1, const float* bv1,
    const float* bs1,
    const float* wq2, const float* wk2, const float* wv2, const float* ws2,
    const float* we2, const float* bq2, const float* bk2, const float* bv2,
    const float* bs2,
    const float* wq3, const float* wk3, const float* wv3, const float* ws3,
    const float* we3, const float* bq3, const float* bk3, const float* bv3,
    const float* bs3,
    __half* W1, float* b1, __half* W2, float* b2, __half* W3, float* b3,
    const float* x, __half* x16, int* cntz, float* doutz) {
  const float SC1 = 0.125f, SC2 = 0.08838834764831845f;
  // fused zeroing: cnt+cursor (CSR build) and d_out (atomic pool target).
  for (int i = blockIdx.x * blockDim.x + threadIdx.x; i < NZERO;
       i += gridDim.x * blockDim.x) {
    if (i < 2 * N_NODES) cntz[i] = 0;
    else doutz[i - 2 * N_NODES] = 0.f;
  }
  for (int i = blockIdx.x * blockDim.x + threadIdx.x; i < TTOT;
       i += gridDim.x * blockDim.x) {
    if (i < T1)
      pack_layer(i, 128, 256, 64, SC1, wq1, wk1, wv1, ws1, we1, bq1, bk1, bv1, bs1, W1, b1);
    else if (i < T2)
      pack_layer(i - T1, 64, 512, 128, SC2, wq2, wk2, wv2, ws2, we2, bq2, bk2, bv2, bs2, W2, b2);
    else if (i < T3)
      pack_layer(i - T2, 128, 256, 64, SC1, wq3, wk3, wv3, ws3, we3, bq3, bk3, bv3, bs3, W3, b3);
    else {
      int k = i - T3;
      float4 v = reinterpret_cast<const float4*>(x)[k];
      __half2* o = reinterpret_cast<__half2*>(x16) + 2 * k;
      o[0] = __floats2half2_rn(v.x, v.y);
      o[1] = __floats2half2_rn(v.z, v.w);
    }
  }
}

// ---------------------------------------------------------------------------
// CSR build over dst
// ---------------------------------------------------------------------------
__global__ void count_dst(const int* __restrict__ dst, int* __restrict__ cnt) {
  int e = blockIdx.x * blockDim.x + threadIdx.x;
  if (e < N_EDGES) atomicAdd(&cnt[dst[e]], 1);
}

// Fused: exclusive scan of degrees -> offs, degree-descending counting sort
// -> perm, AND per-graph inverse counts (for the fused atomic mean-pool).
__global__ __launch_bounds__(1024) void scan_offs(const int* __restrict__ cnt,
                                                  int* __restrict__ offs,
                                                  int* __restrict__ perm,
                                                  const int* __restrict__ batch,
                                                  float* __restrict__ invc) {
  __shared__ int part[1024];
  __shared__ int hist[256], hstart[256], hcur[256];
  const int t = threadIdx.x;
  if (t < N_GRAPHS) {
    int st = lower_bound(batch, N_NODES, t);
    int en = lower_bound(batch, N_NODES, t + 1);
    invc[t] = 1.f / (float)max(en - st, 1);
  }
  const int chunk = (N_NODES + 1023) / 1024;
  const int b = t * chunk;
  const int e = min(N_NODES, b + chunk);
  if (t < 256) { hist[t] = 0; hcur[t] = 0; }
  __syncthreads();
  int s = 0;
  for (int i = b; i < e; ++i) {
    int d = cnt[i];
    s += d;
    atomicAdd(&hist[min(d, 255)], 1);
  }
  part[t] = s;
  __syncthreads();
  for (int off = 1; off < 1024; off <<= 1) {
    int v = (t >= off) ? part[t - off] : 0;
    __syncthreads();
    part[t] += v;
    __syncthreads();
  }
  if (t == 0) {
    int acc = 0;
    for (int bk = 255; bk >= 0; --bk) { hstart[bk] = acc; acc += hist[bk]; }
    offs[N_NODES] = part[1023];
  }
  __syncthreads();
  int pre = (t == 0) ? 0 : part[t - 1];
  for (int i = b; i < e; ++i) {
    offs[i] = pre;
    int d = cnt[i];
    pre += d;
    int bkt = min(d, 255);
    int pos = hstart[bkt] + atomicAdd(&hcur[bkt], 1);
    perm[pos] = i;
  }
}

__global__ void scatter_csr(const int* __restrict__ src, const int* __restrict__ dst,
                            const float* __restrict__ edge_attr,
                            const int* __restrict__ offs, int* __restrict__ cursor,
                            int* __restrict__ csr_src, float* __restrict__ csr_ea) {
  int e = blockIdx.x * blockDim.x + threadIdx.x;
  if (e < N_EDGES) {
    int d = dst[e];
    int pos = offs[d] + atomicAdd(&cursor[d], 1);
    csr_src[pos] = src[e];
    float4* o4 = reinterpret_cast<float4*>(csr_ea + (size_t)pos * 16);
    const float4* s4 = reinterpret_cast<const float4*>(edge_attr + (size_t)e * 16);
    o4[0] = s4[0]; o4[1] = s4[1]; o4[2] = s4[2]; o4[3] = s4[3];
  }
}

// ---------------------------------------------------------------------------
// Fused edge kernel. r5 structure (1 node/wave, depth-3, hoisted index fetch,
// fdot2, fused K|V for NV==1) with two changes:
//  (1) __launch_bounds__(128, 3): VGPR cap ~170, residency hint ~12 waves/CU
//      -> stops the allocator from sinking the pipelined loads (r5 VGPR=84
//      proves the 3-stage buffers were not kept live; true depth-3 needs
//      ~130+ regs).
//  (2) POOL=true (final layer): epilogue atomically accumulates o*invc[g]
//      into d_out directly (pool_all kernel removed).
// ---------------------------------------------------------------------------
template <int DOUT, bool POOL>
__global__ __launch_bounds__(128, 3) void edge_attn(
    const __half* __restrict__ QS, const __half* __restrict__ KV,
    const float* __restrict__ we, const int* __restrict__ csr_src,
    const float* __restrict__ csr_ea, const int* __restrict__ offs,
    const int* __restrict__ perm, const int* __restrict__ batch,
    const float* __restrict__ invc, float* __restrict__ out,
    __half* __restrict__ out16) {
  constexpr int HD = 4 * DOUT;
  constexpr int QSS = HD + 64 + DOUT;
  constexpr int KVS = 2 * HD;
  constexpr int NV = DOUT / 64;
  using KWT = typename KW<NV>::T;

  const int lane = threadIdx.x & 63;
  const int h = lane >> 4, t16 = lane & 15;
  const int n = perm[blockIdx.x * 2 + (threadIdx.x >> 6)];  // N_NODES % 2 == 0
  const int c0 = t16 * 4 * NV;
  const int kvoff = h * 128 + t16 * 8;

  const __half* base = QS + (size_t)n * QSS;
  KWT qw = *reinterpret_cast<const KWT*>(base + h * DOUT + c0);
  float4 acc[NV];
#pragma unroll
  for (int v = 0; v < NV; ++v) acc[v] = make_float4(0.f, 0.f, 0.f, 0.f);
  const float g = __half2float(base[HD + h * 16 + t16]);  // pre-scaled G

  float lsum = 0.f, tacc = 0.f;

  const int s0 = offs[n], s1 = offs[n + 1];

  float eaA[4], eaB[4], eaC[4];
  uint4 krA[4], vrA[4], krB[4], vrB[4], krC[4], vrC[4];

  for (int cb = s0; cb < s1; cb += 64) {
    const int m = min(64, s1 - cb);
    const int idx = csr_src[cb + min(lane, m - 1)];  // coalesced, once/chunk
    const int ng = m >> 2;

    auto load_grp = [&](int gb, float (&ea)[4], uint4 (&kr)[4], uint4 (&vr)[4]) {
      const int bi = cb + gb;
#pragma unroll
      for (int j = 0; j < 4; ++j) ea[j] = csr_ea[(size_t)(bi + j) * 16 + t16];
#pragma unroll
      for (int j = 0; j < 4; ++j) {
        int sj = __shfl(idx, gb + j);
        const __half* rb = KV + (size_t)sj * KVS + kvoff;
        kr[j] = *reinterpret_cast<const uint4*>(rb);
        if (NV == 2) vr[j] = *reinterpret_cast<const uint4*>(rb + HD);
      }
    };

    auto compute_grp = [&](float (&ea)[4], uint4 (&kr)[4], uint4 (&vr)[4]) {
      float a[4];
#pragma unroll
      for (int j = 0; j < 4; ++j) {
        if (NV == 1)
          a[j] = dot_qk(make_uint2(kr[j].x, kr[j].y),
                        *reinterpret_cast<const uint2*>(&qw), ea[j] * g);
        else
          a[j] = dot_qk(*reinterpret_cast<const uint4*>(&kr[j]),
                        *reinterpret_cast<const uint4*>(&qw), ea[j] * g);
      }
#pragma unroll
      for (int j = 0; j < 4; ++j) {
        a[j] += __shfl_xor(a[j], 1);
        a[j] += __shfl_xor(a[j], 2);
        a[j] += __shfl_xor(a[j], 4);
        a[j] += __shfl_xor(a[j], 8);
      }
      float p0 = __expf(a[0]), p1 = __expf(a[1]);
      float p2 = __expf(a[2]), p3 = __expf(a[3]);
      lsum += p0 + p1 + p2 + p3;
      tacc += p0 * ea[0] + p1 * ea[1] + p2 * ea[2] + p3 * ea[3];
      float pj[4] = {p0, p1, p2, p3};
#pragma unroll
      for (int j = 0; j < 4; ++j) {
        float4 vv[NV];
        if (NV == 1)
          cvt_kv(make_uint2(kr[j].z, kr[j].w), vv);
        else
          cvt_kv(vr[j], vv);
#pragma unroll
        for (int v = 0; v < NV; ++v) {
          acc[v].x += pj[j] * vv[v].x;
          acc[v].y += pj[j] * vv[v].y;
          acc[v].z += pj[j] * vv[v].z;
          acc[v].w += pj[j] * vv[v].w;
        }
      }
    };

    if (ng) {
      load_grp(0, eaA, krA, vrA);
      if (ng > 1) load_grp(4, eaB, krB, vrB);
      int gi = 0;
      for (;;) {
        if (gi + 2 < ng) load_grp((gi + 2) * 4, eaC, krC, vrC);
        compute_grp(eaA, krA, vrA);
        if (++gi >= ng) break;
        if (gi + 2 < ng) load_grp((gi + 2) * 4, eaA, krA, vrA);
        compute_grp(eaB, krB, vrB);
        if (++gi >= ng) break;
        if (gi + 2 < ng) load_grp((gi + 2) * 4, eaB, krB, vrB);
        compute_grp(eaC, krC, vrC);
        if (++gi >= ng) break;
      }
    }

    // tail (m & 3 edges)
    for (int e = ng * 4; e < m; ++e) {
      int sj = __shfl(idx, e);
      float ea0 = csr_ea[(size_t)(cb + e) * 16 + t16];
      const __half* rb = KV + (size_t)sj * KVS + kvoff;
      uint4 kw = *reinterpret_cast<const uint4*>(rb);
      float a;
      float4 vv[NV];
      if (NV == 1) {
        a = dot_qk(make_uint2(kw.x, kw.y),
                   *reinterpret_cast<const uint2*>(&qw), ea0 * g);
        cvt_kv(make_uint2(kw.z, kw.w), vv);
      } else {
        uint4 vw = *reinterpret_cast<const uint4*>(rb + HD);
        a = dot_qk(kw, *reinterpret_cast<const uint4*>(&qw), ea0 * g);
        cvt_kv(vw, vv);
      }
      a += __shfl_xor(a, 1);
      a += __shfl_xor(a, 2);
      a += __shfl_xor(a, 4);
      a += __shfl_xor(a, 8);
      float p = __expf(a);
      lsum += p;
      tacc += p * ea0;
#pragma unroll
      for (int v = 0; v < NV; ++v) {
        acc[v].x += p * vv[v].x;
        acc[v].y += p * vv[v].y;
        acc[v].z += p * vv[v].z;
        acc[v].w += p * vv[v].w;
      }
    }
  }

  // epilogue: normalize, add (sum attn*ea)@we, head mean, skip, ELU
  float invl = (lsum > 0.f) ? 1.f / lsum : 0.f;
  float tn = tacc * invl;
  float4 val[NV];
#pragma unroll
  for (int v = 0; v < NV; ++v) {
    val[v].x = acc[v].x * invl; val[v].y = acc[v].y * invl;
    val[v].z = acc[v].z * invl; val[v].w = acc[v].w * invl;
  }
#pragma unroll
  for (int d = 0; d < 16; ++d) {
    float td = __shfl(tn, (lane & 48) | d);
    const float* wb = we + d * HD + h * DOUT + c0;
#pragma unroll
    for (int v = 0; v < NV; ++v) {
      float4 w4 = *reinterpret_cast<const float4*>(wb + 4 * v);
      val[v].x += td * w4.x; val[v].y += td * w4.y;
      val[v].z += td * w4.z; val[v].w += td * w4.w;
    }
  }
#pragma unroll
  for (int v = 0; v < NV; ++v) {
    val[v].x += __shfl_xor(val[v].x, 16); val[v].x += __shfl_xor(val[v].x, 32);
    val[v].y += __shfl_xor(val[v].y, 16); val[v].y += __shfl_xor(val[v].y, 32);
    val[v].z += __shfl_xor(val[v].z, 16); val[v].z += __shfl_xor(val[v].z, 32);
    val[v].w += __shfl_xor(val[v].w, 16); val[v].w += __shfl_xor(val[v].w, 32);
  }
  if (h == 0) {
    KWT sw = *reinterpret_cast<const KWT*>(base + HD + 64 + c0);
    float4 sk[NV];
    cvt_kv(sw, sk);
    float pinv;
    float* gb;
    if (POOL) {
      int gg = batch[n];
      pinv = invc[gg];
      gb = out + gg * 64;
    }
#pragma unroll
    for (int v = 0; v < NV; ++v) {
      float4 o;
      o.x = 0.25f * val[v].x + sk[v].x;
      o.y = 0.25f * val[v].y + sk[v].y;
      o.z = 0.25f * val[v].z + sk[v].z;
      o.w = 0.25f * val[v].w + sk[v].w;
      o.x = (o.x > 0.f) ? o.x : expm1f(o.x);
      o.y = (o.y > 0.f) ? o.y : expm1f(o.y);
      o.z = (o.z > 0.f) ? o.z : expm1f(o.z);
      o.w = (o.w > 0.f) ? o.w : expm1f(o.w);
      if (POOL) {
        float* op = gb + c0 + 4 * v;
        atomicAdd(op + 0, o.x * pinv);
        atomicAdd(op + 1, o.y * pinv);
        atomicAdd(op + 2, o.z * pinv);
        atomicAdd(op + 3, o.w * pinv);
      } else {
        __half2* o16 = reinterpret_cast<__half2*>(out16 + (size_t)n * DOUT + c0 + 4 * v);
        o16[0] = __floats2half2_rn(o.x, o.y);
        o16[1] = __floats2half2_rn(o.z, o.w);
      }
    }
  }
}

// ---------------------------------------------------------------------------
extern "C" void kernel_launch(void* const* d_in, const int* in_sizes, int n_in,
                              void* d_out, int out_size, void* d_ws, size_t ws_size,
                              hipStream_t stream) {
  const float* x = (const float*)d_in[0];
  const int* edge_index = (const int*)d_in[1];
  const float* edge_attr = (const float*)d_in[2];
  const int* batch = (const int*)d_in[3];
  const int* srcp = edge_index;
  const int* dstp = edge_index + N_EDGES;

  const bool dict_order = in_sizes[5] > 1024;
  const float *wq[3], *wk[3], *wv[3], *wep[3], *wsk[3], *bq[3], *bk[3], *bv[3], *bs[3];
  for (int L = 0; L < 3; ++L) {
    int b = 4 + L * 9;
    if (dict_order) {
      wq[L] = (const float*)d_in[b + 0];
      wk[L] = (const float*)d_in[b + 1];
      wv[L] = (const float*)d_in[b + 2];
      wep[L] = (const float*)d_in[b + 3];
      wsk[L] = (const float*)d_in[b + 4];
      bq[L] = (const float*)d_in[b + 5];
      bk[L] = (const float*)d_in[b + 6];
      bv[L] = (const float*)d_in[b + 7];
      bs[L] = (const float*)d_in[b + 8];
    } else {
      wq[L] = (const float*)d_in[b + 0];
      bq[L] = (const float*)d_in[b + 1];
      wk[L] = (const float*)d_in[b + 2];
      bk[L] = (const float*)d_in[b + 3];
      wv[L] = (const float*)d_in[b + 4];
      bv[L] = (const float*)d_in[b + 5];
      wep[L] = (const float*)d_in[b + 6];
      wsk[L] = (const float*)d_in[b + 7];
      bs[L] = (const float*)d_in[b + 8];
    }
  }

  // Workspace carve (bytes).
  char* p = (char*)d_ws;
  __half* qs = (__half*)p;    p += (size_t)N_NODES * 704 * 2;   // Q|G|S f16 (max L2)
  __half* kv = (__half*)p;    p += (size_t)N_NODES * 1024 * 2;  // K|V f16 (max L2)
  float* h1 = (float*)p;      p += (size_t)N_NODES * 64 * 4;
  __half* x16 = (__half*)p;   p += (size_t)N_NODES * 128 * 2;
  __half* h16 = (__half*)p;   p += (size_t)N_NODES * 128 * 2;
  __half* W1 = (__half*)p;    p += 128 * 896 * 2;
  __half* W2 = (__half*)p;    p += 64 * 1728 * 2;
  __half* W3 = (__half*)p;    p += 128 * 896 * 2;
  float* b1 = (float*)p;      p += 896 * 4;
  float* b2 = (float*)p;      p += 1728 * 4;
  float* b3 = (float*)p;      p += 896 * 4;
  float* invc = (float*)p;    p += 64 * 4;
  float* csr_ea = (float*)p;  p += (size_t)N_EDGES * 16 * 4;
  int* cnt = (int*)p;         p += N_NODES * 4;
  int* cursor = (int*)p;      p += N_NODES * 4;
  int* offs = (int*)p;        p += (N_NODES + 1) * 4;
  int* perm = (int*)p;        p += N_NODES * 4;
  int* csr_src = (int*)p;     p += N_EDGES * 4;

  // ---- pack weights + x->f16 + zero(cnt,cursor,d_out) (1 launch) ----
  pack_all<<<1024, 256, 0, stream>>>(
      wq[0], wk[0], wv[0], wsk[0], wep[0], bq[0], bk[0], bv[0], bs[0],
      wq[1], wk[1], wv[1], wsk[1], wep[1], bq[1], bk[1], bv[1], bs[1],
      wq[2], wk[2], wv[2], wsk[2], wep[2], bq[2], bk[2], bv[2], bs[2],
      W1, b1, W2, b2, W3, b3, x, x16, cnt, (float*)d_out);

  // ---- CSR build over dst + degree-sorted perm + per-graph inv counts ----
  count_dst<<<(N_EDGES + 255) / 256, 256, 0, stream>>>(dstp, cnt);
  scan_offs<<<1, 1024, 0, stream>>>(cnt, offs, perm, batch, invc);
  scatter_csr<<<(N_EDGES + 255) / 256, 256, 0, stream>>>(srcp, dstp, edge_attr,
                                                         offs, cursor, csr_src, csr_ea);

  const int MT = (N_NODES + 63) / 64;
  // ---- layer 1: K=128, HD=256, DOUT=64 ----
  gemm_mfma<128, 256, 64><<<dim3(896 / 64, MT), 256, 0, stream>>>(x16, W1, b1, qs,
                                                                  kv, N_NODES);
  edge_attn<64, false><<<N_NODES / 2, 128, 0, stream>>>(
      qs, kv, wep[0], csr_src, csr_ea, offs, perm, batch, invc, h1, h16);
  // ---- layer 2: K=64, HD=512, DOUT=128 ----
  gemm_mfma<64, 512, 128><<<dim3(1728 / 64, MT), 256, 0, stream>>>(h16, W2, b2, qs,
                                                                   kv, N_NODES);
  edge_attn<128, false><<<N_NODES / 2, 128, 0, stream>>>(
      qs, kv, wep[1], csr_src, csr_ea, offs, perm, batch, invc, h1, h16);
  // ---- layer 3: K=128, HD=256, DOUT=64, fused atomic mean-pool ----
  gemm_mfma<128, 256, 64><<<dim3(896 / 64, MT), 256, 0, stream>>>(h16, W3, b3, qs,
                                                                  kv, N_NODES);
  edge_attn<64, true><<<N_NODES / 2, 128, 0, stream>>>(
      qs, kv, wep[2], csr_src, csr_ea, offs, perm, batch, invc, (float*)d_out, x16);
}

// Round 8
// 322.703 us; speedup vs baseline: 1.0856x; 1.0082x over previous
//
#include <hip/hip_runtime.h>
#include <hip/hip_fp16.h>
#include <math.h>

#define N_NODES 10000
#define N_EDGES 160000
#define N_GRAPHS 64

using half8 = __attribute__((ext_vector_type(8))) _Float16;
using floatx4 = __attribute__((ext_vector_type(4))) float;
using h2v = __attribute__((ext_vector_type(2))) _Float16;

// per-lane KV/Q word: DL=2 halfs (DOUT=64) or DL=4 halfs (DOUT=128)
template <int DL> struct QW2;
template <> struct QW2<2> { using T = unsigned int; };
template <> struct QW2<4> { using T = uint2; };

__device__ inline void cvt_v(const unsigned int& w, float* dst) {
  float2 a = __half22float2(*reinterpret_cast<const __half2*>(&w));
  dst[0] = a.x; dst[1] = a.y;
}
__device__ inline void cvt_v(const uint2& w, float* dst) {
  float2 a = __half22float2(*reinterpret_cast<const __half2*>(&w.x));
  float2 b = __half22float2(*reinterpret_cast<const __half2*>(&w.y));
  dst[0] = a.x; dst[1] = a.y; dst[2] = b.x; dst[3] = b.y;
}

// Q.K dot in f16 via v_dot2_f32_f16 (f32 accumulate).
#if __has_builtin(__builtin_amdgcn_fdot2)
__device__ inline float dot_qk(const unsigned int& k, const unsigned int& q, float c) {
  return __builtin_amdgcn_fdot2(__builtin_bit_cast(h2v, k), __builtin_bit_cast(h2v, q), c, false);
}
__device__ inline float dot_qk(const uint2& k, const uint2& q, float c) {
  c = __builtin_amdgcn_fdot2(__builtin_bit_cast(h2v, k.x), __builtin_bit_cast(h2v, q.x), c, false);
  c = __builtin_amdgcn_fdot2(__builtin_bit_cast(h2v, k.y), __builtin_bit_cast(h2v, q.y), c, false);
  return c;
}
#else
__device__ inline float dot_qk(const unsigned int& k, const unsigned int& q, float c) {
  float kk[2], qq[2];
  cvt_v(k, kk); cvt_v(q, qq);
  return c + qq[0] * kk[0] + qq[1] * kk[1];
}
__device__ inline float dot_qk(const uint2& k, const uint2& q, float c) {
  float kk[4], qq[4];
  cvt_v(k, kk); cvt_v(q, qq);
  return c + qq[0] * kk[0] + qq[1] * kk[1] + qq[2] * kk[2] + qq[3] * kk[3];
}
#endif

__device__ inline int lower_bound(const int* b, int n, int v) {
  int lo = 0, hi = n;
  while (lo < hi) {
    int mid = (lo + hi) >> 1;
    if (b[mid] < v) lo = mid + 1; else hi = mid;
  }
  return lo;
}

// ---------------------------------------------------------------------------
// MFMA GEMM: [Q|G|K|V|S] = A[M,K]_f16 @ Wp_f16 + bias_f32. Plain layout
// (the NV==1 K|V interleave was measured neutral and is reverted).
// ---------------------------------------------------------------------------
template <int K, int HD, int DOUT>
__global__ __launch_bounds__(256) void gemm_mfma(
    const __half* __restrict__ A, const __half* __restrict__ Wp,
    const float* __restrict__ bias, __half* __restrict__ QS,
    __half* __restrict__ KV, int M) {
  constexpr int QSS = HD + 64 + DOUT;
  constexpr int KVS = 2 * HD;
  constexpr int KS = K / 32;
  __shared__ __half st[64][72];
  const int tid = threadIdx.x;
  const int wave = tid >> 6, lane = tid & 63;
  const int quad = lane >> 4, n16 = lane & 15;
  const int row0 = blockIdx.y * 64;
  const int col0 = blockIdx.x * 64;
  const int nblk0 = blockIdx.x * 4;

  const int arow = min(row0 + wave * 16 + n16, M - 1);
  half8 afrag[KS];
#pragma unroll
  for (int s = 0; s < KS; ++s)
    afrag[s] = *reinterpret_cast<const half8*>(A + (size_t)arow * K + s * 32 + quad * 8);

  floatx4 acc[4];
#pragma unroll
  for (int t = 0; t < 4; ++t) {
    acc[t] = (floatx4){0.f, 0.f, 0.f, 0.f};
#pragma unroll
    for (int s = 0; s < KS; ++s) {
      half8 bf = *reinterpret_cast<const half8*>(
          Wp + (((size_t)(nblk0 + t) * KS + s) * 64 + lane) * 8);
      acc[t] = __builtin_amdgcn_mfma_f32_16x16x32_f16(afrag[s], bf, acc[t], 0, 0, 0);
    }
  }

#pragma unroll
  for (int t = 0; t < 4; ++t) {
    float bv = bias[col0 + t * 16 + n16];
#pragma unroll
    for (int r = 0; r < 4; ++r)
      st[wave * 16 + quad * 4 + r][t * 16 + n16] = __float2half(acc[t][r] + bv);
  }
  __syncthreads();

  __half* dp;
  int colb, stride;
  if (col0 < HD + 64) {
    dp = QS; colb = col0; stride = QSS;
  } else if (col0 < 3 * HD + 64) {
    dp = KV; colb = col0 - HD - 64; stride = KVS;
  } else {
    dp = QS; colb = HD + 64 + (col0 - 3 * HD - 64); stride = QSS;
  }
  for (int c = tid; c < 512; c += 256) {
    int r = c >> 3, seg = c & 7;
    int row = row0 + r;
    if (row < M)
      *reinterpret_cast<uint4*>(dp + (size_t)row * stride + colb + seg * 8) =
          *reinterpret_cast<const uint4*>(&st[r][seg * 8]);
  }
}

// ---------------------------------------------------------------------------
// Pack weights into B-fragment order (f16), with fused G columns.
// ---------------------------------------------------------------------------
__device__ inline void pack_layer(int i, int K, int HD, int DOUT, float scale,
                                  const float* wq, const float* wk,
                                  const float* wv, const float* wsk,
                                  const float* we, const float* bq,
                                  const float* bk, const float* bv,
                                  const float* bs, __half* Wp, float* bcat) {
  const int W = 3 * HD + DOUT + 64;
  const int KS = K / 32;
  if (i < K * W) {
    int j = i & 7, lane = (i >> 3) & 63, fs = i >> 9;
    int nblk = fs / KS, s = fs - nblk * KS;
    int quad = lane >> 4, n = lane & 15;
    int k = s * 32 + quad * 8 + j, c = nblk * 16 + n;
    float v;
    if (c < HD) {
      v = wq[k * HD + c] * scale;
    } else if (c < HD + 64) {
      int gi = c - HD, hh = gi >> 4, d = gi & 15;
      float a = 0.f;
      for (int cc = 0; cc < DOUT; ++cc)
        a += wq[k * HD + hh * DOUT + cc] * we[d * HD + hh * DOUT + cc];
      v = a * scale;
    } else if (c < 2 * HD + 64) {
      v = wk[k * HD + (c - HD - 64)];
    } else if (c < 3 * HD + 64) {
      v = wv[k * HD + (c - 2 * HD - 64)];
    } else {
      v = wsk[k * DOUT + (c - 3 * HD - 64)];
    }
    Wp[i] = __float2half(v);
  } else {
    int c = i - K * W;
    float v;
    if (c < HD) {
      v = bq[c] * scale;
    } else if (c < HD + 64) {
      int gi = c - HD, hh = gi >> 4, d = gi & 15;
      float a = 0.f;
      for (int cc = 0; cc < DOUT; ++cc)
        a += bq[hh * DOUT + cc] * we[d * HD + hh * DOUT + cc];
      v = a * scale;
    } else if (c < 2 * HD + 64) {
      v = bk[c - HD - 64];
    } else if (c < 3 * HD + 64) {
      v = bv[c - 2 * HD - 64];
    } else {
      v = bs[c - 3 * HD - 64];
    }
    bcat[c] = v;
  }
}

#define T1 115584            // 128*896 + 896
#define T2 227904            // T1 + 64*1728 + 1728
#define T3 343488            // T2 + 128*896 + 896
#define TCONV (N_NODES * 32) // x float4 count
#define TTOT (T3 + TCONV)
#define NZERO (2 * N_NODES + N_GRAPHS * 64)  // cnt+cursor ints, d_out floats

__global__ void pack_all(
    const float* wq1, const float* wk1, const float* wv1, const float* ws1,
    const float* we1, const float* bq1, const float* bk1, const float* bv1,
    const float* bs1,
    const float* wq2, const float* wk2, const float* wv2, const float* ws2,
    const float* we2, const float* bq2, const float* bk2, const float* bv2,
    const float* bs2,
    const float* wq3, const float* wk3, const float* wv3, const float* ws3,
    const float* we3, const float* bq3, const float* bk3, const float* bv3,
    const float* bs3,
    __half* W1, float* b1, __half* W2, float* b2, __half* W3, float* b3,
    const float* x, __half* x16, int* cntz, float* doutz) {
  const float SC1 = 0.125f, SC2 = 0.08838834764831845f;
  for (int i = blockIdx.x * blockDim.x + threadIdx.x; i < NZERO;
       i += gridDim.x * blockDim.x) {
    if (i < 2 * N_NODES) cntz[i] = 0;
    else doutz[i - 2 * N_NODES] = 0.f;
  }
  for (int i = blockIdx.x * blockDim.x + threadIdx.x; i < TTOT;
       i += gridDim.x * blockDim.x) {
    if (i < T1)
      pack_layer(i, 128, 256, 64, SC1, wq1, wk1, wv1, ws1, we1, bq1, bk1, bv1, bs1, W1, b1);
    else if (i < T2)
      pack_layer(i - T1, 64, 512, 128, SC2, wq2, wk2, wv2, ws2, we2, bq2, bk2, bv2, bs2, W2, b2);
    else if (i < T3)
      pack_layer(i - T2, 128, 256, 64, SC1, wq3, wk3, wv3, ws3, we3, bq3, bk3, bv3, bs3, W3, b3);
    else {
      int k = i - T3;
      float4 v = reinterpret_cast<const float4*>(x)[k];
      __half2* o = reinterpret_cast<__half2*>(x16) + 2 * k;
      o[0] = __floats2half2_rn(v.x, v.y);
      o[1] = __floats2half2_rn(v.z, v.w);
    }
  }
}

// ---------------------------------------------------------------------------
// CSR build over dst
// ---------------------------------------------------------------------------
__global__ void count_dst(const int* __restrict__ dst, int* __restrict__ cnt) {
  int e = blockIdx.x * blockDim.x + threadIdx.x;
  if (e < N_EDGES) atomicAdd(&cnt[dst[e]], 1);
}

__global__ __launch_bounds__(1024) void scan_offs(const int* __restrict__ cnt,
                                                  int* __restrict__ offs,
                                                  int* __restrict__ perm,
                                                  const int* __restrict__ batch,
                                                  float* __restrict__ invc) {
  __shared__ int part[1024];
  __shared__ int hist[256], hstart[256], hcur[256];
  const int t = threadIdx.x;
  if (t < N_GRAPHS) {
    int st = lower_bound(batch, N_NODES, t);
    int en = lower_bound(batch, N_NODES, t + 1);
    invc[t] = 1.f / (float)max(en - st, 1);
  }
  const int chunk = (N_NODES + 1023) / 1024;
  const int b = t * chunk;
  const int e = min(N_NODES, b + chunk);
  if (t < 256) { hist[t] = 0; hcur[t] = 0; }
  __syncthreads();
  int s = 0;
  for (int i = b; i < e; ++i) {
    int d = cnt[i];
    s += d;
    atomicAdd(&hist[min(d, 255)], 1);
  }
  part[t] = s;
  __syncthreads();
  for (int off = 1; off < 1024; off <<= 1) {
    int v = (t >= off) ? part[t - off] : 0;
    __syncthreads();
    part[t] += v;
    __syncthreads();
  }
  if (t == 0) {
    int acc = 0;
    for (int bk = 255; bk >= 0; --bk) { hstart[bk] = acc; acc += hist[bk]; }
    offs[N_NODES] = part[1023];
  }
  __syncthreads();
  int pre = (t == 0) ? 0 : part[t - 1];
  for (int i = b; i < e; ++i) {
    offs[i] = pre;
    int d = cnt[i];
    pre += d;
    int bkt = min(d, 255);
    int pos = hstart[bkt] + atomicAdd(&hcur[bkt], 1);
    perm[pos] = i;
  }
}

__global__ void scatter_csr(const int* __restrict__ src, const int* __restrict__ dst,
                            const float* __restrict__ edge_attr,
                            const int* __restrict__ offs, int* __restrict__ cursor,
                            int* __restrict__ csr_src, float* __restrict__ csr_ea) {
  int e = blockIdx.x * blockDim.x + threadIdx.x;
  if (e < N_EDGES) {
    int d = dst[e];
    int pos = offs[d] + atomicAdd(&cursor[d], 1);
    csr_src[pos] = src[e];
    float4* o4 = reinterpret_cast<float4*>(csr_ea + (size_t)pos * 16);
    const float4* s4 = reinterpret_cast<const float4*>(edge_attr + (size_t)e * 16);
    o4[0] = s4[0]; o4[1] = s4[1]; o4[2] = s4[2]; o4[3] = s4[3];
  }
}

// ---------------------------------------------------------------------------
// Fused edge kernel — HEAD-PAIR SPLIT. Block = 1 node = 2 waves; each wave
// owns 2 of the 4 heads (32 lanes/head, DL=DOUT/32 halfs per lane). Doubles
// wave count to 20000 -> ~2x aggregate in-flight gather requests (measured
// regime: latency/queue-bound, BW 3.0/6.3 TB/s, Occ 26%, nothing saturated).
// Cross-head-pair combine via 1KB LDS + one __syncthreads in the epilogue.
// Depth-3 pipeline, hoisted index fetch, fdot2 retained.
// ---------------------------------------------------------------------------
template <int DOUT, bool POOL>
__global__ __launch_bounds__(128) void edge_attn(
    const __half* __restrict__ QS, const __half* __restrict__ KV,
    const float* __restrict__ we, const int* __restrict__ csr_src,
    const float* __restrict__ csr_ea, const int* __restrict__ offs,
    const int* __restrict__ perm, const int* __restrict__ batch,
    const float* __restrict__ invc, float* __restrict__ out,
    __half* __restrict__ out16) {
  constexpr int HD = 4 * DOUT;
  constexpr int QSS = HD + 64 + DOUT;
  constexpr int KVS = 2 * HD;
  constexpr int DL = DOUT / 32;  // halfs per lane
  using QT = typename QW2<DL>::T;

  __shared__ float lds[2][DOUT];

  const int tid = threadIdx.x;
  const int hp = tid >> 6;        // head-pair (= wave id in block)
  const int lane = tid & 63;
  const int h_local = lane >> 5;  // head within pair
  const int head = hp * 2 + h_local;
  const int t32 = lane & 31;
  const int c0 = t32 * DL;        // dim offset within head
  const int n = perm[blockIdx.x];

  const __half* base = QS + (size_t)n * QSS;
  QT qw = *reinterpret_cast<const QT*>(base + head * DOUT + c0);
  // G contribution only from lanes t32<16 (dims 0..15); others masked to 0.
  const float gg = (t32 < 16) ? __half2float(base[HD + head * 16 + t32]) : 0.f;
  const int eoff = t32 & 15;

  float acc[DL];
#pragma unroll
  for (int i = 0; i < DL; ++i) acc[i] = 0.f;
  float lsum = 0.f, tacc = 0.f;

  const int s0 = offs[n], s1 = offs[n + 1];
  const int kvoff = head * DOUT + c0;

  float eaA[4], eaB[4], eaC[4];
  QT krA[4], vrA[4], krB[4], vrB[4], krC[4], vrC[4];

  for (int cb = s0; cb < s1; cb += 64) {
    const int m = min(64, s1 - cb);
    const int idx = csr_src[cb + min(lane, m - 1)];  // coalesced, once/chunk
    const int ng = m >> 2;

    auto load_grp = [&](int gb, float (&ea)[4], QT (&kr)[4], QT (&vr)[4]) {
      const int bi = cb + gb;
#pragma unroll
      for (int j = 0; j < 4; ++j) ea[j] = csr_ea[(size_t)(bi + j) * 16 + eoff];
#pragma unroll
      for (int j = 0; j < 4; ++j) {
        int sj = __shfl(idx, gb + j);
        const __half* rb = KV + (size_t)sj * KVS + kvoff;
        kr[j] = *reinterpret_cast<const QT*>(rb);
        vr[j] = *reinterpret_cast<const QT*>(rb + HD);
      }
    };

    auto compute_grp = [&](float (&ea)[4], QT (&kr)[4], QT (&vr)[4]) {
      float a[4];
#pragma unroll
      for (int j = 0; j < 4; ++j) a[j] = dot_qk(kr[j], qw, ea[j] * gg);
#pragma unroll
      for (int j = 0; j < 4; ++j) {
        a[j] += __shfl_xor(a[j], 1);
        a[j] += __shfl_xor(a[j], 2);
        a[j] += __shfl_xor(a[j], 4);
        a[j] += __shfl_xor(a[j], 8);
        a[j] += __shfl_xor(a[j], 16);
      }
      float p0 = __expf(a[0]), p1 = __expf(a[1]);
      float p2 = __expf(a[2]), p3 = __expf(a[3]);
      lsum += p0 + p1 + p2 + p3;
      // tacc on lanes t32>=16 is garbage (dup ea dims) but never read.
      tacc += p0 * ea[0] + p1 * ea[1] + p2 * ea[2] + p3 * ea[3];
      float pj[4] = {p0, p1, p2, p3};
#pragma unroll
      for (int j = 0; j < 4; ++j) {
        float vv[DL];
        cvt_v(vr[j], vv);
#pragma unroll
        for (int i = 0; i < DL; ++i) acc[i] += pj[j] * vv[i];
      }
    };

    if (ng) {
      load_grp(0, eaA, krA, vrA);
      if (ng > 1) load_grp(4, eaB, krB, vrB);
      int gi = 0;
      for (;;) {
        if (gi + 2 < ng) load_grp((gi + 2) * 4, eaC, krC, vrC);
        compute_grp(eaA, krA, vrA);
        if (++gi >= ng) break;
        if (gi + 2 < ng) load_grp((gi + 2) * 4, eaA, krA, vrA);
        compute_grp(eaB, krB, vrB);
        if (++gi >= ng) break;
        if (gi + 2 < ng) load_grp((gi + 2) * 4, eaB, krB, vrB);
        compute_grp(eaC, krC, vrC);
        if (++gi >= ng) break;
      }
    }

    // tail (m & 3 edges)
    for (int e = ng * 4; e < m; ++e) {
      int sj = __shfl(idx, e);
      float ea0 = csr_ea[(size_t)(cb + e) * 16 + eoff];
      const __half* rb = KV + (size_t)sj * KVS + kvoff;
      QT kw = *reinterpret_cast<const QT*>(rb);
      QT vw = *reinterpret_cast<const QT*>(rb + HD);
      float a = dot_qk(kw, qw, ea0 * gg);
      a += __shfl_xor(a, 1);
      a += __shfl_xor(a, 2);
      a += __shfl_xor(a, 4);
      a += __shfl_xor(a, 8);
      a += __shfl_xor(a, 16);
      float p = __expf(a);
      lsum += p;
      tacc += p * ea0;
      float vv[DL];
      cvt_v(vw, vv);
#pragma unroll
      for (int i = 0; i < DL; ++i) acc[i] += p * vv[i];
    }
  }

  // epilogue: normalize, add (sum attn*ea)@we, head mean, skip, ELU
  float invl = (lsum > 0.f) ? 1.f / lsum : 0.f;
  float tn = tacc * invl;
  float val[DL];
#pragma unroll
  for (int i = 0; i < DL; ++i) val[i] = acc[i] * invl;
#pragma unroll
  for (int d = 0; d < 16; ++d) {
    float td = __shfl(tn, (lane & 32) | d);  // per-head tn lives in t32<16
    const float* wb = we + d * HD + head * DOUT + c0;
#pragma unroll
    for (int i = 0; i < DL; ++i) val[i] += td * wb[i];
  }
  // sum over the 2 heads of this wave (same dims, h_local 0<->1)
#pragma unroll
  for (int i = 0; i < DL; ++i) val[i] += __shfl_xor(val[i], 32);
  if (lane < 32) {
#pragma unroll
    for (int i = 0; i < DL; ++i) lds[hp][c0 + i] = val[i];
  }
  __syncthreads();
  if (hp == 0 && lane < 32) {
    float sk[DL];
    QT sw = *reinterpret_cast<const QT*>(base + HD + 64 + c0);
    cvt_v(sw, sk);
    float o[DL];
#pragma unroll
    for (int i = 0; i < DL; ++i) {
      float tot = 0.25f * (val[i] + lds[1][c0 + i]) + sk[i];
      o[i] = (tot > 0.f) ? tot : expm1f(tot);
    }
    if (POOL) {
      int gg2 = batch[n];
      float pinv = invc[gg2];
      float* op = out + gg2 * 64 + c0;
#pragma unroll
      for (int i = 0; i < DL; ++i) atomicAdd(op + i, o[i] * pinv);
    } else {
      __half2* o16 = reinterpret_cast<__half2*>(out16 + (size_t)n * DOUT + c0);
#pragma unroll
      for (int i = 0; i < DL / 2; ++i)
        o16[i] = __floats2half2_rn(o[2 * i], o[2 * i + 1]);
    }
  }
}

// ---------------------------------------------------------------------------
extern "C" void kernel_launch(void* const* d_in, const int* in_sizes, int n_in,
                              void* d_out, int out_size, void* d_ws, size_t ws_size,
                              hipStream_t stream) {
  const float* x = (const float*)d_in[0];
  const int* edge_index = (const int*)d_in[1];
  const float* edge_attr = (const float*)d_in[2];
  const int* batch = (const int*)d_in[3];
  const int* srcp = edge_index;
  const int* dstp = edge_index + N_EDGES;

  const bool dict_order = in_sizes[5] > 1024;
  const float *wq[3], *wk[3], *wv[3], *wep[3], *wsk[3], *bq[3], *bk[3], *bv[3], *bs[3];
  for (int L = 0; L < 3; ++L) {
    int b = 4 + L * 9;
    if (dict_order) {
      wq[L] = (const float*)d_in[b + 0];
      wk[L] = (const float*)d_in[b + 1];
      wv[L] = (const float*)d_in[b + 2];
      wep[L] = (const float*)d_in[b + 3];
      wsk[L] = (const float*)d_in[b + 4];
      bq[L] = (const float*)d_in[b + 5];
      bk[L] = (const float*)d_in[b + 6];
      bv[L] = (const float*)d_in[b + 7];
      bs[L] = (const float*)d_in[b + 8];
    } else {
      wq[L] = (const float*)d_in[b + 0];
      bq[L] = (const float*)d_in[b + 1];
      wk[L] = (const float*)d_in[b + 2];
      bk[L] = (const float*)d_in[b + 3];
      wv[L] = (const float*)d_in[b + 4];
      bv[L] = (const float*)d_in[b + 5];
      wep[L] = (const float*)d_in[b + 6];
      wsk[L] = (const float*)d_in[b + 7];
      bs[L] = (const float*)d_in[b + 8];
    }
  }

  // Workspace carve (bytes).
  char* p = (char*)d_ws;
  __half* qs = (__half*)p;    p += (size_t)N_NODES * 704 * 2;   // Q|G|S f16 (max L2)
  __half* kv = (__half*)p;    p += (size_t)N_NODES * 1024 * 2;  // K|V f16 (max L2)
  float* h1 = (float*)p;      p += (size_t)N_NODES * 64 * 4;
  __half* x16 = (__half*)p;   p += (size_t)N_NODES * 128 * 2;
  __half* h16 = (__half*)p;   p += (size_t)N_NODES * 128 * 2;
  __half* W1 = (__half*)p;    p += 128 * 896 * 2;
  __half* W2 = (__half*)p;    p += 64 * 1728 * 2;
  __half* W3 = (__half*)p;    p += 128 * 896 * 2;
  float* b1 = (float*)p;      p += 896 * 4;
  float* b2 = (float*)p;      p += 1728 * 4;
  float* b3 = (float*)p;      p += 896 * 4;
  float* invc = (float*)p;    p += 64 * 4;
  float* csr_ea = (float*)p;  p += (size_t)N_EDGES * 16 * 4;
  int* cnt = (int*)p;         p += N_NODES * 4;
  int* cursor = (int*)p;      p += N_NODES * 4;
  int* offs = (int*)p;        p += (N_NODES + 1) * 4;
  int* perm = (int*)p;        p += N_NODES * 4;
  int* csr_src = (int*)p;     p += N_EDGES * 4;

  // ---- pack weights + x->f16 + zero(cnt,cursor,d_out) (1 launch) ----
  pack_all<<<1024, 256, 0, stream>>>(
      wq[0], wk[0], wv[0], wsk[0], wep[0], bq[0], bk[0], bv[0], bs[0],
      wq[1], wk[1], wv[1], wsk[1], wep[1], bq[1], bk[1], bv[1], bs[1],
      wq[2], wk[2], wv[2], wsk[2], wep[2], bq[2], bk[2], bv[2], bs[2],
      W1, b1, W2, b2, W3, b3, x, x16, cnt, (float*)d_out);

  // ---- CSR build over dst + degree-sorted perm + per-graph inv counts ----
  count_dst<<<(N_EDGES + 255) / 256, 256, 0, stream>>>(dstp, cnt);
  scan_offs<<<1, 1024, 0, stream>>>(cnt, offs, perm, batch, invc);
  scatter_csr<<<(N_EDGES + 255) / 256, 256, 0, stream>>>(srcp, dstp, edge_attr,
                                                         offs, cursor, csr_src, csr_ea);

  const int MT = (N_NODES + 63) / 64;
  // ---- layer 1: K=128, HD=256, DOUT=64 ----
  gemm_mfma<128, 256, 64><<<dim3(896 / 64, MT), 256, 0, stream>>>(x16, W1, b1, qs,
                                                                  kv, N_NODES);
  edge_attn<64, false><<<N_NODES, 128, 0, stream>>>(
      qs, kv, wep[0], csr_src, csr_ea, offs, perm, batch, invc, h1, h16);
  // ---- layer 2: K=64, HD=512, DOUT=128 ----
  gemm_mfma<64, 512, 128><<<dim3(1728 / 64, MT), 256, 0, stream>>>(h16, W2, b2, qs,
                                                                   kv, N_NODES);
  edge_attn<128, false><<<N_NODES, 128, 0, stream>>>(
      qs, kv, wep[1], csr_src, csr_ea, offs, perm, batch, invc, h1, h16);
  // ---- layer 3: K=128, HD=256, DOUT=64, fused atomic mean-pool ----
  gemm_mfma<128, 256, 64><<<dim3(896 / 64, MT), 256, 0, stream>>>(h16, W3, b3, qs,
                                                                  kv, N_NODES);
  edge_attn<64, true><<<N_NODES, 128, 0, stream>>>(
      qs, kv, wep[2], csr_src, csr_ea, offs, perm, batch, invc, (float*)d_out, x16);
}